// Round 6
// baseline (615.863 us; speedup 1.0000x reference)
//
#include <hip/hip_runtime.h>

#define N_NODES 50000
#define N_EDGES 800000
#define IN_DIM  128
#define EDGE_DIM 64
#define OUT_DIM 128
#define NTILES  (N_EDGES / 128)   // 6250 exact

typedef __attribute__((ext_vector_type(8))) short bf16x8;
typedef __attribute__((ext_vector_type(4))) float f32x4;
typedef unsigned short u16;
typedef unsigned long long u64;

__device__ __forceinline__ u16 f2bf(float f) {
    union { float f; unsigned u; } x; x.f = f;
    unsigned r = x.u + 0x7FFFu + ((x.u >> 16) & 1u);
    return (u16)(r >> 16);
}
__device__ __forceinline__ float bf2f(u16 h) {
    union { unsigned u; float f; } x; x.u = ((unsigned)h) << 16;
    return x.f;
}
__device__ __forceinline__ bf16x8 pack8(const float* v) {
    bf16x8 r;
#pragma unroll
    for (int i = 0; i < 8; ++i) r[i] = (short)f2bf(v[i]);
    return r;
}

// ---------------------------------------------------------------------------
// W2fT[o][c] = sum_i W_edge[c][i] * W_ne[IN_DIM + i][o]  (stored [128][64])
// ---------------------------------------------------------------------------
__global__ void fuse_w2_kernel(const float* __restrict__ W_edge,
                               const float* __restrict__ W_ne,
                               float* __restrict__ W2fT) {
    const int idx = blockIdx.x * blockDim.x + threadIdx.x;
    if (idx >= EDGE_DIM * OUT_DIM) return;
    const int c = idx >> 7;
    const int o = idx & 127;
    float acc = 0.0f;
    for (int i = 0; i < OUT_DIM; ++i)
        acc += W_edge[c * OUT_DIM + i] * W_ne[(IN_DIM + i) * OUT_DIM + o];
    W2fT[o * EDGE_DIM + c] = acc;
}

// ---------------------------------------------------------------------------
// Dual node GEMM: H1 = nfeat @ W_ne[:128] (bf16), HS = nfeat @ W_self + b_self
// ---------------------------------------------------------------------------
__global__ __launch_bounds__(256, 2) void node_gemm_dual_kernel(
    const float* __restrict__ nfeat, const float* __restrict__ W_ne,
    const float* __restrict__ W_self, const float* __restrict__ b_self,
    u16* __restrict__ H1, u16* __restrict__ HS) {
    __shared__ float4 hh[4][32];
    const int t = threadIdx.x;
    const int o = t & 127;
    const bool self = (t >= 128);
    const float* W = self ? W_self : W_ne;   // W_ne rows [0,128) == W1
    float w[128];
#pragma unroll
    for (int k = 0; k < 128; ++k) w[k] = W[k * OUT_DIM + o];
    const float b = self ? b_self[o] : 0.0f;
    u16* Y = self ? HS : H1;

    const int npass = N_NODES / 4;
    for (int p = blockIdx.x; p < npass; p += gridDim.x) {
        const int r0 = p * 4;
        if (t < 128) hh[t >> 5][t & 31] = ((const float4*)(nfeat + (size_t)r0 * 128))[t];
        __syncthreads();
        float a0 = b, a1 = b, a2 = b, a3 = b;
#pragma unroll
        for (int k4 = 0; k4 < 32; ++k4) {
            float4 h0 = hh[0][k4], h1 = hh[1][k4], h2 = hh[2][k4], h3 = hh[3][k4];
            a0 = fmaf(h0.x, w[4*k4+0], a0); a0 = fmaf(h0.y, w[4*k4+1], a0);
            a0 = fmaf(h0.z, w[4*k4+2], a0); a0 = fmaf(h0.w, w[4*k4+3], a0);
            a1 = fmaf(h1.x, w[4*k4+0], a1); a1 = fmaf(h1.y, w[4*k4+1], a1);
            a1 = fmaf(h1.z, w[4*k4+2], a1); a1 = fmaf(h1.w, w[4*k4+3], a1);
            a2 = fmaf(h2.x, w[4*k4+0], a2); a2 = fmaf(h2.y, w[4*k4+1], a2);
            a2 = fmaf(h2.z, w[4*k4+2], a2); a2 = fmaf(h2.w, w[4*k4+3], a2);
            a3 = fmaf(h3.x, w[4*k4+0], a3); a3 = fmaf(h3.y, w[4*k4+1], a3);
            a3 = fmaf(h3.z, w[4*k4+2], a3); a3 = fmaf(h3.w, w[4*k4+3], a3);
        }
        Y[(size_t)(r0 + 0) * 128 + o] = f2bf(a0);
        Y[(size_t)(r0 + 1) * 128 + o] = f2bf(a1);
        Y[(size_t)(r0 + 2) * 128 + o] = f2bf(a2);
        Y[(size_t)(r0 + 3) * 128 + o] = f2bf(a3);
        __syncthreads();
    }
}

// ---------------------------------------------------------------------------
// CSR build: count/rank -> scan
// ---------------------------------------------------------------------------
__global__ void count_rank_kernel(const int* __restrict__ dst,
                                  int* __restrict__ counts, int* __restrict__ rank) {
    const int e = blockIdx.x * blockDim.x + threadIdx.x;
    if (e < N_EDGES) rank[e] = atomicAdd(&counts[dst[e]], 1);
}

#define SCAN_T 1024
#define SCAN_CHUNK 49
__global__ void scan_kernel(const int* __restrict__ counts, int* __restrict__ off) {
    __shared__ int part[SCAN_T];
    const int t = threadIdx.x;
    const int base = t * SCAN_CHUNK;
    int s = 0;
    for (int k = 0; k < SCAN_CHUNK; ++k) {
        const int i = base + k;
        if (i < N_NODES) s += counts[i];
    }
    part[t] = s;
    __syncthreads();
    for (int d = 1; d < SCAN_T; d <<= 1) {
        int v = (t >= d) ? part[t - d] : 0;
        __syncthreads();
        part[t] += v;
        __syncthreads();
    }
    int excl = part[t] - s;
    for (int k = 0; k < SCAN_CHUNK; ++k) {
        const int i = base + k;
        if (i < N_NODES) { off[i] = excl; excl += counts[i]; }
    }
    if (t == SCAN_T - 1) off[N_NODES] = excl;
}

// ---------------------------------------------------------------------------
// Permute: efeatS[slot] = bf16(efeat[e]) (dst-sorted), srcS/dstS alongside.
// Sequential fp32 read; random access only on the STORE side (128 B lines).
// ---------------------------------------------------------------------------
__global__ __launch_bounds__(256, 4) void permute_kernel(
    const float* __restrict__ efeat, const int* __restrict__ src,
    const int* __restrict__ dst, const int* __restrict__ rank,
    const int* __restrict__ offs,
    u16* __restrict__ efeatS, int* __restrict__ srcS, int* __restrict__ dstS) {
    const int stride = gridDim.x * blockDim.x;
    for (int he = blockIdx.x * blockDim.x + threadIdx.x; he < N_EDGES * 2; he += stride) {
        const int e  = he >> 1;
        const int hf = he & 1;
        const int d  = dst[e];
        const int slot = offs[d] + rank[e];
        const float4* ep = (const float4*)(efeat + (size_t)e * 64 + hf * 32);
        u16* wp = efeatS + (size_t)slot * 64 + hf * 32;
#pragma unroll
        for (int j = 0; j < 4; ++j) {
            float4 x = ep[2 * j], y = ep[2 * j + 1];
            float tmp[8] = {x.x, x.y, x.z, x.w, y.x, y.y, y.z, y.w};
            *(bf16x8*)(wp + j * 8) = pack8(tmp);
        }
        if (hf == 0) { srcS[slot] = src[e]; dstS[slot] = d; }
    }
}

// ---------------------------------------------------------------------------
// zero the output accumulator (atomic flush targets need 0-init)
// ---------------------------------------------------------------------------
__global__ void zero_out_kernel(float* __restrict__ out) {
    const int stride = gridDim.x * blockDim.x;
    float4 z = {0.f, 0.f, 0.f, 0.f};
    for (int j = blockIdx.x * blockDim.x + threadIdx.x; j < (N_NODES * OUT_DIM) / 4; j += stride)
        ((float4*)out)[j] = z;
}

// ---------------------------------------------------------------------------
// FUSED edge GEMM + segment reduce over dst-sorted slots (all reads sequential):
//   A-tile <- efeatS (bf16, 128-slot tile)  [swizzled LDS]
//   E2 = A @ W2fT + b_ne (MFMA);  v = relu(E2 + H1[srcS])
//   v -> Mb col-major swizzled LDS;  wave-parallel segmented reduce by dstS:
//   ballot boundary mask + register scan; interior segs -> store, open -> atomic.
// ---------------------------------------------------------------------------
__global__ __launch_bounds__(256, 3) void fused_edge_kernel(
    const u16* __restrict__ efeatS, const int* __restrict__ srcS,
    const int* __restrict__ dstS, const float* __restrict__ W2fT,
    const float* __restrict__ b_ne, const u16* __restrict__ H1,
    float* __restrict__ out) {

    __shared__ __align__(16) char Ab[128 * 64 * 2];    // 16 KB A-tile (row-major swz)
    __shared__ __align__(16) char Mb[128 * 128 * 2];   // 32 KB m-tile (col-major swz)
    __shared__ int sS[128];
    __shared__ int dL[128];

    const int tid  = threadIdx.x;
    const int w    = tid >> 6;
    const int l    = tid & 63;
    const int lrow = l & 15;
    const int lq   = l >> 4;

    // B fragments (W2fT) + bias, loaded once per block
    bf16x8 Bf[8][2];
    float bias[8];
#pragma unroll
    for (int nt = 0; nt < 8; ++nt) {
        bias[nt] = b_ne[nt * 16 + lrow];
#pragma unroll
        for (int kk = 0; kk < 2; ++kk) {
            const float* wp = W2fT + (nt * 16 + lrow) * 64 + kk * 32 + lq * 8;
            float tmp[8];
#pragma unroll
            for (int j = 0; j < 8; ++j) tmp[j] = wp[j];
            Bf[nt][kk] = pack8(tmp);
        }
    }

    const int srow = tid >> 1;          // staging row within tile
    const int shf  = tid & 1;           // staging half-row

    for (int tile = blockIdx.x; tile < NTILES; tile += gridDim.x) {
        const int t0 = tile * 128;

        if (tid < 128) {
            sS[tid] = srcS[t0 + tid];
            dL[tid] = dstS[t0 + tid];
        }
        // ---- stage bf16 tile (sequential global read) -> swizzled LDS
        {
            const u16* sp = efeatS + (size_t)(t0 + srow) * 64 + shf * 32;
#pragma unroll
            for (int j = 0; j < 4; ++j) {
                bf16x8 f = *(const bf16x8*)(sp + j * 8);
                const int c = shf * 4 + j;
                const int addr = (srow * 128 + c * 16) ^ ((srow & 7) << 4);
                *(bf16x8*)(Ab + addr) = f;
            }
        }
        __syncthreads();   // Ab, sS, dL ready (prev tile fully consumed)

        // ---- MFMA: E2 = A @ W2fT + bias
        f32x4 acc[2][8];
#pragma unroll
        for (int mt = 0; mt < 2; ++mt)
#pragma unroll
            for (int nt = 0; nt < 8; ++nt) {
                acc[mt][nt][0] = bias[nt]; acc[mt][nt][1] = bias[nt];
                acc[mt][nt][2] = bias[nt]; acc[mt][nt][3] = bias[nt];
            }
        bf16x8 Af[2][2];
#pragma unroll
        for (int mt = 0; mt < 2; ++mt)
#pragma unroll
            for (int kk = 0; kk < 2; ++kk) {
                const int row  = w * 32 + mt * 16 + lrow;
                const int addr = (row * 128 + kk * 64 + lq * 16) ^ ((row & 7) << 4);
                Af[mt][kk] = *(const bf16x8*)(Ab + addr);
            }
#pragma unroll
        for (int mt = 0; mt < 2; ++mt)
#pragma unroll
            for (int nt = 0; nt < 8; ++nt) {
                acc[mt][nt] = __builtin_amdgcn_mfma_f32_16x16x32_bf16(Af[mt][0], Bf[nt][0], acc[mt][nt], 0, 0, 0);
                acc[mt][nt] = __builtin_amdgcn_mfma_f32_16x16x32_bf16(Af[mt][1], Bf[nt][1], acc[mt][nt], 0, 0, 0);
            }

        // ---- epilogue: v = relu(E2 + H1[src]) -> Mb col-major swizzled (b64 packed)
#pragma unroll
        for (int mt = 0; mt < 2; ++mt) {
#pragma unroll
            for (int nt = 0; nt < 8; ++nt) {
                const int col  = nt * 16 + lrow;
                const int row0 = w * 32 + mt * 16 + lq * 4;
                u64 pk = 0;
#pragma unroll
                for (int j = 0; j < 4; ++j) {
                    const u16* hp = H1 + (size_t)sS[row0 + j] * 128;
                    float v = fmaxf(acc[mt][nt][j] + bf2f(hp[col]), 0.0f);
                    pk |= ((u64)f2bf(v)) << (16 * j);
                }
                const int addr = col * 256 + ((row0 * 2) ^ ((col & 7) << 4));
                *(u64*)(Mb + addr) = pk;
            }
        }
        __syncthreads();   // Mb ready

        // ---- wave-parallel segmented reduce
        {
            const int hh    = w >> 1;                 // half (rows hh*64..hh*64+63)
            const int oc    = ((w & 1) << 6) + l;     // column
            const int rbase = hh * 64;

            const int myd   = dL[rbase + l];
            const int prevd = (l > 0) ? dL[rbase + l - 1] : 0;
            const u64 mask  = __ballot(l > 0 && myd != prevd);  // bit r: row r starts new seg

            bf16x8 vv[8];
            const int cswz = (oc & 7) << 4;
#pragma unroll
            for (int g = 0; g < 8; ++g)
                vv[g] = *(const bf16x8*)(Mb + oc * 256 + rbase * 2 + ((g * 16) ^ cswz));

            int a = 0;
            float racc = 0.0f;
#pragma unroll
            for (int r = 0; r < 64; ++r) {
                if (r > 0 && ((mask >> r) & 1ULL)) {
                    // flush [a, r-1] : right-closed (r-1 < 63)
                    const int d = dL[rbase + a];
                    float* p = out + (size_t)d * 128 + oc;
                    if (a > 0) *p = racc;          // fully interior -> exclusive
                    else       atomicAdd(p, racc); // touches half start -> open
                    a = r; racc = 0.0f;
                }
                racc += bf2f((u16)vv[r >> 3][r & 7]);
            }
            {   // final flush [a, 63]
                const int d = dL[rbase + a];
                const bool closed = (a > 0) && (hh == 0) && (dL[64] != d);
                float* p = out + (size_t)d * 128 + oc;
                if (closed) *p = racc;
                else        atomicAdd(p, racc);
            }
        }
        __syncthreads();   // Mb/sS/dL free for next tile
    }
}

// ---------------------------------------------------------------------------
// finalize: out[n] = out[n] / max(cnt[n],1) + HS[n]
// ---------------------------------------------------------------------------
__global__ void finalize_kernel(float* __restrict__ out, const int* __restrict__ counts,
                                const u16* __restrict__ HS) {
    const int stride = gridDim.x * blockDim.x;
    for (int i = blockIdx.x * blockDim.x + threadIdx.x; i < N_NODES * 32; i += stride) {
        const int row = i >> 5;
        const int c = counts[row];
        const float inv = (c > 0) ? 1.0f / (float)c : 0.0f;
        float4 v = ((const float4*)out)[i];
        ushort4 hs = ((const ushort4*)HS)[i];
        float4 r;
        r.x = v.x * inv + bf2f(hs.x);
        r.y = v.y * inv + bf2f(hs.y);
        r.z = v.z * inv + bf2f(hs.z);
        r.w = v.w * inv + bf2f(hs.w);
        ((float4*)out)[i] = r;
    }
}

// ---------------------------------------------------------------------------
extern "C" void kernel_launch(void* const* d_in, const int* in_sizes, int n_in,
                              void* d_out, int out_size, void* d_ws, size_t ws_size,
                              hipStream_t stream) {
    const float* nfeat  = (const float*)d_in[0];
    const float* efeat  = (const float*)d_in[1];
    const int*   src    = (const int*)d_in[2];
    const int*   dst    = (const int*)d_in[3];
    const float* W_edge = (const float*)d_in[4];
    const float* W_ne   = (const float*)d_in[5];
    const float* b_ne   = (const float*)d_in[6];
    const float* W_self = (const float*)d_in[7];
    const float* b_self = (const float*)d_in[8];

    float* out = (float*)d_out;
    char* ws = (char*)d_ws;

    // ws layout (~138 MB; >=237 MB proven available in rounds 3-5)
    const size_t OFF_W2   = 0;          // 32768 B
    const size_t OFF_CNT  = 32768;      // 200192 B (padded)
    const size_t OFF_OFFS = 232960;     // 200192 B (padded)
    const size_t OFF_RANK = 433152;     // 3.2 MB
    const size_t OFF_H1   = 3633152;    // 12.8 MB
    const size_t OFF_HS   = 16433152;   // 12.8 MB
    const size_t OFF_EFS  = 29233152;   // 102.4 MB
    const size_t OFF_SRCS = 131633152;  // 3.2 MB
    const size_t OFF_DSTS = 134833152;  // 3.2 MB -> end 138033152

    float* W2fT   = (float*)(ws + OFF_W2);
    int*   cnts   = (int*)(ws + OFF_CNT);
    int*   offs   = (int*)(ws + OFF_OFFS);
    int*   rank   = (int*)(ws + OFF_RANK);
    u16*   H1     = (u16*)(ws + OFF_H1);
    u16*   HS     = (u16*)(ws + OFF_HS);
    u16*   efeatS = (u16*)(ws + OFF_EFS);
    int*   srcS   = (int*)(ws + OFF_SRCS);
    int*   dstS   = (int*)(ws + OFF_DSTS);

    hipMemsetAsync(cnts, 0, N_NODES * sizeof(int), stream);
    fuse_w2_kernel<<<32, 256, 0, stream>>>(W_edge, W_ne, W2fT);
    node_gemm_dual_kernel<<<2048, 256, 0, stream>>>(nfeat, W_ne, W_self, b_self, H1, HS);
    count_rank_kernel<<<(N_EDGES + 255) / 256, 256, 0, stream>>>(dst, cnts, rank);
    scan_kernel<<<1, SCAN_T, 0, stream>>>(cnts, offs);
    permute_kernel<<<2048, 256, 0, stream>>>(efeat, src, dst, rank, offs, efeatS, srcS, dstS);
    zero_out_kernel<<<2048, 256, 0, stream>>>(out);
    fused_edge_kernel<<<2048, 256, 0, stream>>>(efeatS, srcS, dstS, W2fT, b_ne, H1, out);
    finalize_kernel<<<2048, 256, 0, stream>>>(out, cnts, HS);
}

// Round 7
// 403.431 us; speedup vs baseline: 1.5266x; 1.5266x over previous
//
#include <hip/hip_runtime.h>

#define N_NODES 50000
#define N_EDGES 800000
#define IN_DIM  128
#define EDGE_DIM 64
#define OUT_DIM 128
#define NTILES  (N_EDGES / 128)   // 6250 exact

typedef __attribute__((ext_vector_type(8))) short bf16x8;
typedef __attribute__((ext_vector_type(4))) float f32x4;
typedef unsigned short u16;

__device__ __forceinline__ u16 f2bf(float f) {
    union { float f; unsigned u; } x; x.f = f;
    unsigned r = x.u + 0x7FFFu + ((x.u >> 16) & 1u);
    return (u16)(r >> 16);
}
__device__ __forceinline__ float bf2f(u16 h) {
    union { unsigned u; float f; } x; x.u = ((unsigned)h) << 16;
    return x.f;
}
__device__ __forceinline__ bf16x8 pack8(const float* v) {
    bf16x8 r;
#pragma unroll
    for (int i = 0; i < 8; ++i) r[i] = (short)f2bf(v[i]);
    return r;
}

// ---------------------------------------------------------------------------
// W2fT[o][c] = sum_i W_edge[c][i] * W_ne[IN_DIM + i][o]  (stored [128][64])
// ---------------------------------------------------------------------------
__global__ void fuse_w2_kernel(const float* __restrict__ W_edge,
                               const float* __restrict__ W_ne,
                               float* __restrict__ W2fT) {
    const int idx = blockIdx.x * blockDim.x + threadIdx.x;
    if (idx >= EDGE_DIM * OUT_DIM) return;
    const int c = idx >> 7;
    const int o = idx & 127;
    float acc = 0.0f;
    for (int i = 0; i < OUT_DIM; ++i)
        acc += W_edge[c * OUT_DIM + i] * W_ne[(IN_DIM + i) * OUT_DIM + o];
    W2fT[o * EDGE_DIM + c] = acc;
}

// ---------------------------------------------------------------------------
// Dual node GEMM: H1 = nfeat @ W_ne[:128] (bf16), HS = nfeat @ W_self + b_self
// ---------------------------------------------------------------------------
__global__ __launch_bounds__(256, 2) void node_gemm_dual_kernel(
    const float* __restrict__ nfeat, const float* __restrict__ W_ne,
    const float* __restrict__ W_self, const float* __restrict__ b_self,
    u16* __restrict__ H1, u16* __restrict__ HS) {
    __shared__ float4 hh[4][32];
    const int t = threadIdx.x;
    const int o = t & 127;
    const bool self = (t >= 128);
    const float* W = self ? W_self : W_ne;   // W_ne rows [0,128) == W1
    float w[128];
#pragma unroll
    for (int k = 0; k < 128; ++k) w[k] = W[k * OUT_DIM + o];
    const float b = self ? b_self[o] : 0.0f;
    u16* Y = self ? HS : H1;

    const int npass = N_NODES / 4;
    for (int p = blockIdx.x; p < npass; p += gridDim.x) {
        const int r0 = p * 4;
        if (t < 128) hh[t >> 5][t & 31] = ((const float4*)(nfeat + (size_t)r0 * 128))[t];
        __syncthreads();
        float a0 = b, a1 = b, a2 = b, a3 = b;
#pragma unroll
        for (int k4 = 0; k4 < 32; ++k4) {
            float4 h0 = hh[0][k4], h1 = hh[1][k4], h2 = hh[2][k4], h3 = hh[3][k4];
            a0 = fmaf(h0.x, w[4*k4+0], a0); a0 = fmaf(h0.y, w[4*k4+1], a0);
            a0 = fmaf(h0.z, w[4*k4+2], a0); a0 = fmaf(h0.w, w[4*k4+3], a0);
            a1 = fmaf(h1.x, w[4*k4+0], a1); a1 = fmaf(h1.y, w[4*k4+1], a1);
            a1 = fmaf(h1.z, w[4*k4+2], a1); a1 = fmaf(h1.w, w[4*k4+3], a1);
            a2 = fmaf(h2.x, w[4*k4+0], a2); a2 = fmaf(h2.y, w[4*k4+1], a2);
            a2 = fmaf(h2.z, w[4*k4+2], a2); a2 = fmaf(h2.w, w[4*k4+3], a2);
            a3 = fmaf(h3.x, w[4*k4+0], a3); a3 = fmaf(h3.y, w[4*k4+1], a3);
            a3 = fmaf(h3.z, w[4*k4+2], a3); a3 = fmaf(h3.w, w[4*k4+3], a3);
        }
        Y[(size_t)(r0 + 0) * 128 + o] = f2bf(a0);
        Y[(size_t)(r0 + 1) * 128 + o] = f2bf(a1);
        Y[(size_t)(r0 + 2) * 128 + o] = f2bf(a2);
        Y[(size_t)(r0 + 3) * 128 + o] = f2bf(a3);
        __syncthreads();
    }
}

// ---------------------------------------------------------------------------
// CSR build: count/rank -> scan -> slotOf (inverse permutation)
// ---------------------------------------------------------------------------
__global__ void count_rank_kernel(const int* __restrict__ dst,
                                  int* __restrict__ counts, int* __restrict__ rank) {
    const int e = blockIdx.x * blockDim.x + threadIdx.x;
    if (e < N_EDGES) rank[e] = atomicAdd(&counts[dst[e]], 1);
}

#define SCAN_T 1024
#define SCAN_CHUNK 49
__global__ void scan_kernel(const int* __restrict__ counts, int* __restrict__ off) {
    __shared__ int part[SCAN_T];
    const int t = threadIdx.x;
    const int base = t * SCAN_CHUNK;
    int s = 0;
    for (int k = 0; k < SCAN_CHUNK; ++k) {
        const int i = base + k;
        if (i < N_NODES) s += counts[i];
    }
    part[t] = s;
    __syncthreads();
    for (int d = 1; d < SCAN_T; d <<= 1) {
        int v = (t >= d) ? part[t - d] : 0;
        __syncthreads();
        part[t] += v;
        __syncthreads();
    }
    int excl = part[t] - s;
    for (int k = 0; k < SCAN_CHUNK; ++k) {
        const int i = base + k;
        if (i < N_NODES) { off[i] = excl; excl += counts[i]; }
    }
    if (t == SCAN_T - 1) off[N_NODES] = excl;
}

__global__ void slotof_kernel(const int* __restrict__ dst, const int* __restrict__ rank,
                              const int* __restrict__ off, int* __restrict__ slotOf) {
    const int e = blockIdx.x * blockDim.x + threadIdx.x;
    if (e < N_EDGES) slotOf[e] = off[dst[e]] + rank[e];
}

// ---------------------------------------------------------------------------
// Edge GEMM with scatter-write (sequential efeat read, proven R5 kernel):
//   m[e] = relu(efeat[e] @ W2f + H1[src[e]] + b_ne)  -> mbuf[slotOf[e]] (bf16)
// Random access only on the STORE side (latency-tolerant).
// ---------------------------------------------------------------------------
__global__ __launch_bounds__(256, 2) void edge_gemm_scatter_kernel(
    const float* __restrict__ efeat, const int* __restrict__ src,
    const int* __restrict__ slotOf, const float* __restrict__ W2fT,
    const float* __restrict__ b_ne, const u16* __restrict__ H1,
    u16* __restrict__ mbuf) {

    __shared__ __align__(16) char Ab[128 * 64 * 2];
    __shared__ int sS[128];   // src per row
    __shared__ int sT[128];   // slot per row

    const int tid  = threadIdx.x;
    const int w    = tid >> 6;
    const int l    = tid & 63;
    const int lrow = l & 15;
    const int lq   = l >> 4;

    bf16x8 Bf[8][2];
    float bias[8];
#pragma unroll
    for (int nt = 0; nt < 8; ++nt) {
        bias[nt] = b_ne[nt * 16 + lrow];
#pragma unroll
        for (int kk = 0; kk < 2; ++kk) {
            const float* wp = W2fT + (nt * 16 + lrow) * 64 + kk * 32 + lq * 8;
            float tmp[8];
#pragma unroll
            for (int j = 0; j < 8; ++j) tmp[j] = wp[j];
            Bf[nt][kk] = pack8(tmp);
        }
    }

    const int srow = tid >> 1;
    const int skh  = (tid & 1) * 32;

    for (int tile = blockIdx.x; tile < NTILES; tile += gridDim.x) {
        const int e0 = tile * 128;

        if (tid < 128) {
            sS[tid] = src[e0 + tid];
            sT[tid] = slotOf[e0 + tid];
        }
        // ---- stage efeat rows (sequential) -> bf16 swizzled LDS
        const float4* ep = (const float4*)(efeat + (size_t)(e0 + srow) * 64 + skh);
#pragma unroll
        for (int j = 0; j < 4; ++j) {
            float4 x = ep[2 * j], y = ep[2 * j + 1];
            float tmp[8] = {x.x, x.y, x.z, x.w, y.x, y.y, y.z, y.w};
            bf16x8 f = pack8(tmp);
            int addr = (srow * 128 + skh * 2 + j * 16) ^ ((srow & 7) << 4);
            *(bf16x8*)(Ab + addr) = f;
        }
        __syncthreads();   // Ab, sS, sT ready

        f32x4 acc[2][8];
#pragma unroll
        for (int mt = 0; mt < 2; ++mt)
#pragma unroll
            for (int nt = 0; nt < 8; ++nt) {
                acc[mt][nt][0] = bias[nt]; acc[mt][nt][1] = bias[nt];
                acc[mt][nt][2] = bias[nt]; acc[mt][nt][3] = bias[nt];
            }
        bf16x8 Af[2][2];
#pragma unroll
        for (int mt = 0; mt < 2; ++mt)
#pragma unroll
            for (int kk = 0; kk < 2; ++kk) {
                int row  = w * 32 + mt * 16 + lrow;
                int addr = (row * 128 + kk * 64 + lq * 16) ^ ((row & 7) << 4);
                Af[mt][kk] = *(const bf16x8*)(Ab + addr);
            }
#pragma unroll
        for (int mt = 0; mt < 2; ++mt)
#pragma unroll
            for (int nt = 0; nt < 8; ++nt) {
                acc[mt][nt] = __builtin_amdgcn_mfma_f32_16x16x32_bf16(Af[mt][0], Bf[nt][0], acc[mt][nt], 0, 0, 0);
                acc[mt][nt] = __builtin_amdgcn_mfma_f32_16x16x32_bf16(Af[mt][1], Bf[nt][1], acc[mt][nt], 0, 0, 0);
            }

        // ---- epilogue: gather H1[src], relu, scatter bf16 row to mbuf[slot]
#pragma unroll
        for (int mt = 0; mt < 2; ++mt) {
#pragma unroll
            for (int j = 0; j < 4; ++j) {
                const int row = w * 32 + mt * 16 + lq * 4 + j;
                const u16* hp = H1 + (size_t)sS[row] * 128;
                u16* mp = mbuf + (size_t)sT[row] * 128;
#pragma unroll
                for (int nt = 0; nt < 8; ++nt) {
                    const int col = nt * 16 + lrow;
                    float v = fmaxf(acc[mt][nt][j] + bf2f(hp[col]), 0.0f);
                    mp[col] = f2bf(v);
                }
            }
        }
        __syncthreads();   // Ab/sS/sT free for next tile
    }
}

// ---------------------------------------------------------------------------
// Wave-per-node segment reduce + finalize (vectorized bf16x8 loads):
//   lanes: cs = l&15 -> 8-column slot, rg = l>>4 -> 4 rows in flight.
//   out[n] = (sum of mbuf rows [off[n],off[n+1]))/max(deg,1) + HS[n]
// ---------------------------------------------------------------------------
__global__ __launch_bounds__(256, 4) void reduce_kernel(
    const int* __restrict__ off, const u16* __restrict__ mbuf,
    const u16* __restrict__ HS, float* __restrict__ out) {
    const int n = (blockIdx.x * blockDim.x + threadIdx.x) >> 6;  // wave id = node
    if (n >= N_NODES) return;
    const int l  = threadIdx.x & 63;
    const int cs = l & 15;        // column slot (8 cols)
    const int rg = l >> 4;        // row group (4 rows in flight)
    const int s0 = off[n], s1 = off[n + 1];

    float facc[8];
#pragma unroll
    for (int i = 0; i < 8; ++i) facc[i] = 0.0f;
    for (int s = s0 + rg; s < s1; s += 4) {
        bf16x8 v = *(const bf16x8*)(mbuf + (size_t)s * 128 + cs * 8);
#pragma unroll
        for (int i = 0; i < 8; ++i) facc[i] += bf2f((u16)v[i]);
    }
#pragma unroll
    for (int i = 0; i < 8; ++i) {
        facc[i] += __shfl_xor(facc[i], 16, 64);
        facc[i] += __shfl_xor(facc[i], 32, 64);
    }
    if (rg == 0) {
        const int c = s1 - s0;
        const float inv = (c > 0) ? 1.0f / (float)c : 0.0f;
        bf16x8 hs = *(const bf16x8*)(HS + (size_t)n * 128 + cs * 8);
        float4 o0, o1;
        o0.x = facc[0] * inv + bf2f((u16)hs[0]);
        o0.y = facc[1] * inv + bf2f((u16)hs[1]);
        o0.z = facc[2] * inv + bf2f((u16)hs[2]);
        o0.w = facc[3] * inv + bf2f((u16)hs[3]);
        o1.x = facc[4] * inv + bf2f((u16)hs[4]);
        o1.y = facc[5] * inv + bf2f((u16)hs[5]);
        o1.z = facc[6] * inv + bf2f((u16)hs[6]);
        o1.w = facc[7] * inv + bf2f((u16)hs[7]);
        float* op = out + (size_t)n * 128 + cs * 8;
        *(float4*)op = o0;
        *(float4*)(op + 4) = o1;
    }
}

// ---------------------------------------------------------------------------
extern "C" void kernel_launch(void* const* d_in, const int* in_sizes, int n_in,
                              void* d_out, int out_size, void* d_ws, size_t ws_size,
                              hipStream_t stream) {
    const float* nfeat  = (const float*)d_in[0];
    const float* efeat  = (const float*)d_in[1];
    const int*   src    = (const int*)d_in[2];
    const int*   dst    = (const int*)d_in[3];
    const float* W_edge = (const float*)d_in[4];
    const float* W_ne   = (const float*)d_in[5];
    const float* b_ne   = (const float*)d_in[6];
    const float* W_self = (const float*)d_in[7];
    const float* b_self = (const float*)d_in[8];

    float* out = (float*)d_out;
    char* ws = (char*)d_ws;

    // ws layout (~237.2 MB; proven available in rounds 3-6)
    const size_t OFF_W2   = 0;                        // 32768 B
    const size_t OFF_CNT  = 32768;                    // 200000 B
    const size_t OFF_OFFS = OFF_CNT + 200000;         // 200064 B
    const size_t OFF_RANK = OFF_OFFS + 200064;        // 3.2 MB
    const size_t OFF_SLOT = OFF_RANK + 3200000;       // 3.2 MB
    const size_t OFF_H1   = OFF_SLOT + 3200000;       // 12.8 MB
    const size_t OFF_HS   = OFF_H1 + 12800000;        // 12.8 MB
    const size_t OFF_M    = OFF_HS + 12800000;        // 204.8 MB

    float* W2fT   = (float*)(ws + OFF_W2);
    int*   cnts   = (int*)(ws + OFF_CNT);
    int*   offs   = (int*)(ws + OFF_OFFS);
    int*   rank   = (int*)(ws + OFF_RANK);
    int*   slotOf = (int*)(ws + OFF_SLOT);
    u16*   H1     = (u16*)(ws + OFF_H1);
    u16*   HS     = (u16*)(ws + OFF_HS);
    u16*   mbuf   = (u16*)(ws + OFF_M);

    hipMemsetAsync(cnts, 0, N_NODES * sizeof(int), stream);
    fuse_w2_kernel<<<32, 256, 0, stream>>>(W_edge, W_ne, W2fT);
    node_gemm_dual_kernel<<<2048, 256, 0, stream>>>(nfeat, W_ne, W_self, b_self, H1, HS);
    count_rank_kernel<<<(N_EDGES + 255) / 256, 256, 0, stream>>>(dst, cnts, rank);
    scan_kernel<<<1, SCAN_T, 0, stream>>>(cnts, offs);
    slotof_kernel<<<(N_EDGES + 255) / 256, 256, 0, stream>>>(dst, rank, offs, slotOf);
    edge_gemm_scatter_kernel<<<2048, 256, 0, stream>>>(efeat, src, slotOf, W2fT, b_ne, H1, mbuf);
    reduce_kernel<<<(N_NODES * 64 + 255) / 256, 256, 0, stream>>>(offs, mbuf, HS, out);
}

// Round 9
// 376.616 us; speedup vs baseline: 1.6353x; 1.0712x over previous
//
#include <hip/hip_runtime.h>

#define N_NODES 50000
#define N_EDGES 800000
#define IN_DIM  128
#define EDGE_DIM 64
#define OUT_DIM 128
#define NTILES  (N_EDGES / 128)   // 6250 exact
#define NODE_TILES ((N_NODES + 127) / 128)  // 391

typedef __attribute__((ext_vector_type(8))) short bf16x8;
typedef __attribute__((ext_vector_type(4))) float f32x4;
typedef unsigned short u16;

__device__ __forceinline__ u16 f2bf(float f) {
    union { float f; unsigned u; } x; x.f = f;
    unsigned r = x.u + 0x7FFFu + ((x.u >> 16) & 1u);
    return (u16)(r >> 16);
}
__device__ __forceinline__ float bf2f(u16 h) {
    union { unsigned u; float f; } x; x.u = ((unsigned)h) << 16;
    return x.f;
}
__device__ __forceinline__ bf16x8 pack8(const float* v) {
    bf16x8 r;
#pragma unroll
    for (int i = 0; i < 8; ++i) r[i] = (short)f2bf(v[i]);
    return r;
}

// ---------------------------------------------------------------------------
// W2fT[o][c] = sum_i W_edge[c][i] * W_ne[IN_DIM + i][o]  (stored [128][64])
// ---------------------------------------------------------------------------
__global__ void fuse_w2_kernel(const float* __restrict__ W_edge,
                               const float* __restrict__ W_ne,
                               float* __restrict__ W2fT) {
    const int idx = blockIdx.x * blockDim.x + threadIdx.x;
    if (idx >= EDGE_DIM * OUT_DIM) return;
    const int c = idx >> 7;
    const int o = idx & 127;
    float acc = 0.0f;
    for (int i = 0; i < OUT_DIM; ++i)
        acc += W_edge[c * OUT_DIM + i] * W_ne[(IN_DIM + i) * OUT_DIM + o];
    W2fT[o * EDGE_DIM + c] = acc;
}

// ---------------------------------------------------------------------------
// MFMA node GEMM (swapped operands): per 128-row tile compute
//   H1[n] = nfeat[n] @ W1 (bf16),  HS[n] = nfeat[n] @ W_self + b_self (bf16)
// 4 waves: wave w owns out-cols w*64..+64 of the 256-col (H1||HS) output.
// ---------------------------------------------------------------------------
__global__ __launch_bounds__(256, 1) void node_gemm_mfma_kernel(
    const float* __restrict__ nfeat, const float* __restrict__ W_ne,
    const float* __restrict__ W_self, const float* __restrict__ b_self,
    u16* __restrict__ H1, u16* __restrict__ HS) {

    __shared__ __align__(16) char Nb[128 * 128 * 2];   // 32 KB bf16 tile

    const int tid  = threadIdx.x;
    const int w    = tid >> 6;
    const int l    = tid & 63;
    const int lrow = l & 15;
    const int lq   = l >> 4;

    const bool isSelf = (w >= 2);
    const float* W = isSelf ? W_self : W_ne;   // [128][128] row-major (k rows)
    const int colw = (w & 1) * 64;             // col base within its matrix
    u16* Y = isSelf ? HS : H1;

    // A-side weight fragments: Wf[mt][kk] = W^T[colw+mt*16+lrow][kk*32+lq*8..]
    bf16x8 Wf[4][4];
#pragma unroll
    for (int mt = 0; mt < 4; ++mt) {
        const int c = colw + mt * 16 + lrow;
#pragma unroll
        for (int kk = 0; kk < 4; ++kk) {
            float tmp[8];
#pragma unroll
            for (int t = 0; t < 8; ++t) tmp[t] = W[(kk * 32 + lq * 8 + t) * 128 + c];
            Wf[mt][kk] = pack8(tmp);
        }
    }
    float4 bias4[4];
#pragma unroll
    for (int mt = 0; mt < 4; ++mt) {
        if (isSelf) bias4[mt] = *(const float4*)(b_self + colw + mt * 16 + lq * 4);
        else { bias4[mt].x = 0.f; bias4[mt].y = 0.f; bias4[mt].z = 0.f; bias4[mt].w = 0.f; }
    }

    const int srow = tid >> 1;
    const int skc  = (tid & 1) * 8;    // starting 16B-chunk index (8 chunks each)

    for (int tile = blockIdx.x; tile < NODE_TILES; tile += gridDim.x) {
        const int r0 = tile * 128;
        // ---- stage nfeat rows -> bf16 swizzled LDS ([128][128] bf16, 256B rows)
        {
            const int gr = min(r0 + srow, N_NODES - 1);
            // FIX (R8 bug): chunk = 8 floats -> float offset = skc * 8 (was skc*4)
            const float4* np = (const float4*)(nfeat + (size_t)gr * 128 + skc * 8);
            const int swz = (srow & 7);
#pragma unroll
            for (int j = 0; j < 8; ++j) {
                float4 x = np[2 * j], y = np[2 * j + 1];
                float tmp[8] = {x.x, x.y, x.z, x.w, y.x, y.y, y.z, y.w};
                bf16x8 f = pack8(tmp);
                const int kc = skc + j;
                *(bf16x8*)(Nb + srow * 256 + (((kc) ^ swz) * 16)) = f;
            }
        }
        __syncthreads();

        f32x4 acc[4][8];
#pragma unroll
        for (int mt = 0; mt < 4; ++mt)
#pragma unroll
            for (int nt = 0; nt < 8; ++nt) {
                acc[mt][nt][0] = bias4[mt].x; acc[mt][nt][1] = bias4[mt].y;
                acc[mt][nt][2] = bias4[mt].z; acc[mt][nt][3] = bias4[mt].w;
            }
#pragma unroll
        for (int nt = 0; nt < 8; ++nt) {
            const int r = nt * 16 + lrow;
            const int swz = (r & 7);
            bf16x8 Be[4];
#pragma unroll
            for (int kk = 0; kk < 4; ++kk)
                Be[kk] = *(const bf16x8*)(Nb + r * 256 + (((kk * 4 + lq) ^ swz) * 16));
#pragma unroll
            for (int mt = 0; mt < 4; ++mt)
#pragma unroll
                for (int kk = 0; kk < 4; ++kk)
                    acc[mt][nt] = __builtin_amdgcn_mfma_f32_16x16x32_bf16(Wf[mt][kk], Be[kk], acc[mt][nt], 0, 0, 0);
        }

        // ---- store: lane owns cols colw+mt*16+lq*4..+4 of row nt*16+lrow
#pragma unroll
        for (int nt = 0; nt < 8; ++nt) {
            const int n = r0 + nt * 16 + lrow;
            if (n < N_NODES) {
#pragma unroll
                for (int mt = 0; mt < 4; ++mt) {
                    const int c0 = colw + mt * 16 + lq * 4;
                    ushort4 o;
                    o.x = f2bf(acc[mt][nt][0]); o.y = f2bf(acc[mt][nt][1]);
                    o.z = f2bf(acc[mt][nt][2]); o.w = f2bf(acc[mt][nt][3]);
                    *(ushort4*)(Y + (size_t)n * 128 + c0) = o;
                }
            }
        }
        __syncthreads();
    }
}

// ---------------------------------------------------------------------------
// CSR build: count/rank -> scan -> slotOf (inverse permutation)
// ---------------------------------------------------------------------------
__global__ void count_rank_kernel(const int* __restrict__ dst,
                                  int* __restrict__ counts, int* __restrict__ rank) {
    const int e = blockIdx.x * blockDim.x + threadIdx.x;
    if (e < N_EDGES) rank[e] = atomicAdd(&counts[dst[e]], 1);
}

#define SCAN_T 1024
#define SCAN_CHUNK 49
__global__ void scan_kernel(const int* __restrict__ counts, int* __restrict__ off) {
    __shared__ int part[SCAN_T];
    const int t = threadIdx.x;
    const int base = t * SCAN_CHUNK;
    int s = 0;
    for (int k = 0; k < SCAN_CHUNK; ++k) {
        const int i = base + k;
        if (i < N_NODES) s += counts[i];
    }
    part[t] = s;
    __syncthreads();
    for (int d = 1; d < SCAN_T; d <<= 1) {
        int v = (t >= d) ? part[t - d] : 0;
        __syncthreads();
        part[t] += v;
        __syncthreads();
    }
    int excl = part[t] - s;
    for (int k = 0; k < SCAN_CHUNK; ++k) {
        const int i = base + k;
        if (i < N_NODES) { off[i] = excl; excl += counts[i]; }
    }
    if (t == SCAN_T - 1) off[N_NODES] = excl;
}

__global__ void slotof_kernel(const int* __restrict__ dst, const int* __restrict__ rank,
                              const int* __restrict__ off, int* __restrict__ slotOf) {
    const int e = blockIdx.x * blockDim.x + threadIdx.x;
    if (e < N_EDGES) slotOf[e] = off[dst[e]] + rank[e];
}

// ---------------------------------------------------------------------------
// Edge GEMM, swapped operands + double-buffered staging:
//   m[e] = relu(efeat[e] @ W2f + H1[src[e]] + b_ne)  -> mbuf[slotOf[e]] (bf16)
// Lane owns 4 consecutive out-cols per (mt,nt) -> ushort4 H1 loads and
// ushort4 mbuf stores. Next tile's global loads issue before MFMA (T14).
// ---------------------------------------------------------------------------
__global__ __launch_bounds__(256, 2) void edge_gemm_scatter_kernel(
    const float* __restrict__ efeat, const int* __restrict__ src,
    const int* __restrict__ slotOf, const float* __restrict__ W2fT,
    const float* __restrict__ b_ne, const u16* __restrict__ H1,
    u16* __restrict__ mbuf) {

    __shared__ __align__(16) char Ab[2][128 * 64 * 2];  // 2 x 16 KB
    __shared__ int sS[2][128];
    __shared__ int sT[2][128];

    const int tid  = threadIdx.x;
    const int w    = tid >> 6;
    const int l    = tid & 63;
    const int lrow = l & 15;
    const int lq   = l >> 4;

    // A-side W2f fragments + per-reg bias (cols w*32+mt*16+lq*4+j)
    bf16x8 Wf[2][2];
    float4 bias4[2];
#pragma unroll
    for (int mt = 0; mt < 2; ++mt) {
        const int c = w * 32 + mt * 16 + lrow;
#pragma unroll
        for (int kk = 0; kk < 2; ++kk) {
            const float* wp = W2fT + c * 64 + kk * 32 + lq * 8;
            float tmp[8];
#pragma unroll
            for (int j = 0; j < 8; ++j) tmp[j] = wp[j];
            Wf[mt][kk] = pack8(tmp);
        }
        bias4[mt] = *(const float4*)(b_ne + w * 32 + mt * 16 + lq * 4);
    }

    const int srow = tid >> 1;
    const int skh  = (tid & 1) * 32;   // k-half in floats
    const int G    = gridDim.x;

    // ---- prologue: stage tile blockIdx into buffer 0
    int tile = blockIdx.x;
    {
        const float4* ep = (const float4*)(efeat + (size_t)(tile * 128 + srow) * 64 + skh);
        const int swz = (srow & 7) << 4;
#pragma unroll
        for (int j = 0; j < 4; ++j) {
            float4 x = ep[2 * j], y = ep[2 * j + 1];
            float tmp[8] = {x.x, x.y, x.z, x.w, y.x, y.y, y.z, y.w};
            bf16x8 f = pack8(tmp);
            *(bf16x8*)(Ab[0] + ((srow * 128 + skh * 2 + j * 16) ^ swz)) = f;
        }
        if (tid < 128) {
            sS[0][tid] = src[tile * 128 + tid];
            sT[0][tid] = slotOf[tile * 128 + tid];
        }
    }
    __syncthreads();

    int cur = 0;
    for (; tile < NTILES; tile += G) {
        const int nxt = tile + G;
        // ---- T14: issue next tile's global loads into registers
        float4 pf[8];
        int pS = 0, pT = 0;
        if (nxt < NTILES) {
            const float4* ep = (const float4*)(efeat + (size_t)(nxt * 128 + srow) * 64 + skh);
#pragma unroll
            for (int j = 0; j < 8; ++j) pf[j] = ep[j];
            if (tid < 128) {
                pS = src[nxt * 128 + tid];
                pT = slotOf[nxt * 128 + tid];
            }
        }

        // ---- MFMA: D[out-col][edge] = W2f^T . efeat^T
        f32x4 acc[2][8];
#pragma unroll
        for (int mt = 0; mt < 2; ++mt)
#pragma unroll
            for (int nt = 0; nt < 8; ++nt) {
                acc[mt][nt][0] = bias4[mt].x; acc[mt][nt][1] = bias4[mt].y;
                acc[mt][nt][2] = bias4[mt].z; acc[mt][nt][3] = bias4[mt].w;
            }
#pragma unroll
        for (int nt = 0; nt < 8; ++nt) {
            const int r = nt * 16 + lrow;
            const int swz = (r & 7) << 4;
            bf16x8 Be0 = *(const bf16x8*)(Ab[cur] + ((r * 128 + lq * 16) ^ swz));
            bf16x8 Be1 = *(const bf16x8*)(Ab[cur] + ((r * 128 + 64 + lq * 16) ^ swz));
#pragma unroll
            for (int mt = 0; mt < 2; ++mt) {
                acc[mt][nt] = __builtin_amdgcn_mfma_f32_16x16x32_bf16(Wf[mt][0], Be0, acc[mt][nt], 0, 0, 0);
                acc[mt][nt] = __builtin_amdgcn_mfma_f32_16x16x32_bf16(Wf[mt][1], Be1, acc[mt][nt], 0, 0, 0);
            }
        }

        // ---- epilogue: lane owns cols w*32+mt*16+lq*4..+4 of edge nt*16+lrow
#pragma unroll
        for (int nt = 0; nt < 8; ++nt) {
            const int e  = nt * 16 + lrow;
            const int sn = sS[cur][e];
            const int st = sT[cur][e];
#pragma unroll
            for (int mt = 0; mt < 2; ++mt) {
                const int c0 = w * 32 + mt * 16 + lq * 4;
                ushort4 h4 = *(const ushort4*)(H1 + (size_t)sn * 128 + c0);
                ushort4 o;
                o.x = f2bf(fmaxf(acc[mt][nt][0] + bf2f(h4.x), 0.0f));
                o.y = f2bf(fmaxf(acc[mt][nt][1] + bf2f(h4.y), 0.0f));
                o.z = f2bf(fmaxf(acc[mt][nt][2] + bf2f(h4.z), 0.0f));
                o.w = f2bf(fmaxf(acc[mt][nt][3] + bf2f(h4.w), 0.0f));
                *(ushort4*)(mbuf + (size_t)st * 128 + c0) = o;
            }
        }
        __syncthreads();   // all waves done with Ab/sS/sT[cur] and prior buf

        // ---- write prefetched tile into the other buffer
        if (nxt < NTILES) {
            const int swz = (srow & 7) << 4;
#pragma unroll
            for (int j = 0; j < 4; ++j) {
                float tmp[8] = {pf[2*j].x, pf[2*j].y, pf[2*j].z, pf[2*j].w,
                                pf[2*j+1].x, pf[2*j+1].y, pf[2*j+1].z, pf[2*j+1].w};
                bf16x8 f = pack8(tmp);
                *(bf16x8*)(Ab[cur ^ 1] + ((srow * 128 + skh * 2 + j * 16) ^ swz)) = f;
            }
            if (tid < 128) {
                sS[cur ^ 1][tid] = pS;
                sT[cur ^ 1][tid] = pT;
            }
        }
        __syncthreads();   // next buffer visible to all waves
        cur ^= 1;
    }
}

// ---------------------------------------------------------------------------
// Wave-per-node segment reduce + finalize (vectorized bf16x8 loads)
// ---------------------------------------------------------------------------
__global__ __launch_bounds__(256, 4) void reduce_kernel(
    const int* __restrict__ off, const u16* __restrict__ mbuf,
    const u16* __restrict__ HS, float* __restrict__ out) {
    const int n = (blockIdx.x * blockDim.x + threadIdx.x) >> 6;  // wave id = node
    if (n >= N_NODES) return;
    const int l  = threadIdx.x & 63;
    const int cs = l & 15;        // column slot (8 cols)
    const int rg = l >> 4;        // row group (4 rows in flight)
    const int s0 = off[n], s1 = off[n + 1];

    float facc[8];
#pragma unroll
    for (int i = 0; i < 8; ++i) facc[i] = 0.0f;
    for (int s = s0 + rg; s < s1; s += 4) {
        bf16x8 v = *(const bf16x8*)(mbuf + (size_t)s * 128 + cs * 8);
#pragma unroll
        for (int i = 0; i < 8; ++i) facc[i] += bf2f((u16)v[i]);
    }
#pragma unroll
    for (int i = 0; i < 8; ++i) {
        facc[i] += __shfl_xor(facc[i], 16, 64);
        facc[i] += __shfl_xor(facc[i], 32, 64);
    }
    if (rg == 0) {
        const int c = s1 - s0;
        const float inv = (c > 0) ? 1.0f / (float)c : 0.0f;
        bf16x8 hs = *(const bf16x8*)(HS + (size_t)n * 128 + cs * 8);
        float4 o0, o1;
        o0.x = facc[0] * inv + bf2f((u16)hs[0]);
        o0.y = facc[1] * inv + bf2f((u16)hs[1]);
        o0.z = facc[2] * inv + bf2f((u16)hs[2]);
        o0.w = facc[3] * inv + bf2f((u16)hs[3]);
        o1.x = facc[4] * inv + bf2f((u16)hs[4]);
        o1.y = facc[5] * inv + bf2f((u16)hs[5]);
        o1.z = facc[6] * inv + bf2f((u16)hs[6]);
        o1.w = facc[7] * inv + bf2f((u16)hs[7]);
        float* op = out + (size_t)n * 128 + cs * 8;
        *(float4*)op = o0;
        *(float4*)(op + 4) = o1;
    }
}

// ---------------------------------------------------------------------------
extern "C" void kernel_launch(void* const* d_in, const int* in_sizes, int n_in,
                              void* d_out, int out_size, void* d_ws, size_t ws_size,
                              hipStream_t stream) {
    const float* nfeat  = (const float*)d_in[0];
    const float* efeat  = (const float*)d_in[1];
    const int*   src    = (const int*)d_in[2];
    const int*   dst    = (const int*)d_in[3];
    const float* W_edge = (const float*)d_in[4];
    const float* W_ne   = (const float*)d_in[5];
    const float* b_ne   = (const float*)d_in[6];
    const float* W_self = (const float*)d_in[7];
    const float* b_self = (const float*)d_in[8];

    float* out = (float*)d_out;
    char* ws = (char*)d_ws;

    // ws layout (~237.2 MB; proven available in rounds 3-7)
    const size_t OFF_W2   = 0;                        // 32768 B
    const size_t OFF_CNT  = 32768;                    // 200000 B
    const size_t OFF_OFFS = OFF_CNT + 200000;         // 200064 B
    const size_t OFF_RANK = OFF_OFFS + 200064;        // 3.2 MB
    const size_t OFF_SLOT = OFF_RANK + 3200000;       // 3.2 MB
    const size_t OFF_H1   = OFF_SLOT + 3200000;       // 12.8 MB
    const size_t OFF_HS   = OFF_H1 + 12800000;        // 12.8 MB
    const size_t OFF_M    = OFF_HS + 12800000;        // 204.8 MB

    float* W2fT   = (float*)(ws + OFF_W2);
    int*   cnts   = (int*)(ws + OFF_CNT);
    int*   offs   = (int*)(ws + OFF_OFFS);
    int*   rank   = (int*)(ws + OFF_RANK);
    int*   slotOf = (int*)(ws + OFF_SLOT);
    u16*   H1     = (u16*)(ws + OFF_H1);
    u16*   HS     = (u16*)(ws + OFF_HS);
    u16*   mbuf   = (u16*)(ws + OFF_M);

    hipMemsetAsync(cnts, 0, N_NODES * sizeof(int), stream);
    fuse_w2_kernel<<<32, 256, 0, stream>>>(W_edge, W_ne, W2fT);
    node_gemm_mfma_kernel<<<NODE_TILES, 256, 0, stream>>>(nfeat, W_ne, W_self, b_self, H1, HS);
    count_rank_kernel<<<(N_EDGES + 255) / 256, 256, 0, stream>>>(dst, cnts, rank);
    scan_kernel<<<1, SCAN_T, 0, stream>>>(cnts, offs);
    slotof_kernel<<<(N_EDGES + 255) / 256, 256, 0, stream>>>(dst, rank, offs, slotOf);
    edge_gemm_scatter_kernel<<<2048, 256, 0, stream>>>(efeat, src, slotOf, W2fT, b_ne, H1, mbuf);
    reduce_kernel<<<(N_NODES * 64 + 255) / 256, 256, 0, stream>>>(offs, mbuf, HS, out);
}

// Round 10
// 355.575 us; speedup vs baseline: 1.7320x; 1.0592x over previous
//
#include <hip/hip_runtime.h>

#define N_NODES 50000
#define N_EDGES 800000
#define IN_DIM  128
#define EDGE_DIM 64
#define OUT_DIM 128
#define NTILES  (N_EDGES / 128)             // 6250 exact
#define NODE_TILES ((N_NODES + 127) / 128)  // 391
#define W2_BLOCKS 32
#define ZERO_BLOCKS 196                      // 196*256 = 50176 >= 50000

typedef __attribute__((ext_vector_type(8))) short bf16x8;
typedef __attribute__((ext_vector_type(4))) float f32x4;
typedef unsigned short u16;

__device__ __forceinline__ u16 f2bf(float f) {
    union { float f; unsigned u; } x; x.f = f;
    unsigned r = x.u + 0x7FFFu + ((x.u >> 16) & 1u);
    return (u16)(r >> 16);
}
__device__ __forceinline__ float bf2f(u16 h) {
    union { unsigned u; float f; } x; x.u = ((unsigned)h) << 16;
    return x.f;
}
__device__ __forceinline__ bf16x8 pack8(const float* v) {
    bf16x8 r;
#pragma unroll
    for (int i = 0; i < 8; ++i) r[i] = (short)f2bf(v[i]);
    return r;
}

// ---------------------------------------------------------------------------
// prep_kernel: three independent jobs by block range (saves 2 dispatches)
//   blocks [0, NODE_TILES)              : MFMA node GEMM -> H1, HS (bf16)
//   blocks [NODE_TILES, +W2_BLOCKS)     : W2fT[o][c] fused weight
//   blocks [NODE_TILES+W2_BLOCKS, +196) : zero cnts
// ---------------------------------------------------------------------------
__global__ __launch_bounds__(256, 1) void prep_kernel(
    const float* __restrict__ nfeat, const float* __restrict__ W_ne,
    const float* __restrict__ W_self, const float* __restrict__ b_self,
    const float* __restrict__ W_edge,
    u16* __restrict__ H1, u16* __restrict__ HS,
    float* __restrict__ W2fT, int* __restrict__ cnts) {

    __shared__ __align__(16) char Nb[128 * 128 * 2];   // 32 KB bf16 tile

    const int bid = blockIdx.x;
    const int tid = threadIdx.x;

    if (bid >= NODE_TILES) {
        if (bid < NODE_TILES + W2_BLOCKS) {
            // ---- fused W2: W2fT[o][c] = sum_i W_edge[c][i]*W_ne[128+i][o]
            const int idx = (bid - NODE_TILES) * 256 + tid;
            const int c = idx >> 7;
            const int o = idx & 127;
            float acc = 0.0f;
            for (int i = 0; i < OUT_DIM; ++i)
                acc += W_edge[c * OUT_DIM + i] * W_ne[(IN_DIM + i) * OUT_DIM + o];
            W2fT[o * EDGE_DIM + c] = acc;
        } else {
            const int i = (bid - NODE_TILES - W2_BLOCKS) * 256 + tid;
            if (i < N_NODES) cnts[i] = 0;
        }
        return;
    }

    // ---- node GEMM tile (R9-verified, swapped operands)
    const int w    = tid >> 6;
    const int l    = tid & 63;
    const int lrow = l & 15;
    const int lq   = l >> 4;

    const bool isSelf = (w >= 2);
    const float* W = isSelf ? W_self : W_ne;   // rows [0,128) of W_ne == W1
    const int colw = (w & 1) * 64;
    u16* Y = isSelf ? HS : H1;

    bf16x8 Wf[4][4];
#pragma unroll
    for (int mt = 0; mt < 4; ++mt) {
        const int c = colw + mt * 16 + lrow;
#pragma unroll
        for (int kk = 0; kk < 4; ++kk) {
            float tmp[8];
#pragma unroll
            for (int t = 0; t < 8; ++t) tmp[t] = W[(kk * 32 + lq * 8 + t) * 128 + c];
            Wf[mt][kk] = pack8(tmp);
        }
    }
    float4 bias4[4];
#pragma unroll
    for (int mt = 0; mt < 4; ++mt) {
        if (isSelf) bias4[mt] = *(const float4*)(b_self + colw + mt * 16 + lq * 4);
        else { bias4[mt].x = 0.f; bias4[mt].y = 0.f; bias4[mt].z = 0.f; bias4[mt].w = 0.f; }
    }

    const int srow = tid >> 1;
    const int skc  = (tid & 1) * 8;    // 16B-chunk index (8 floats per chunk)
    const int r0 = bid * 128;
    {
        const int gr = min(r0 + srow, N_NODES - 1);
        const float4* np = (const float4*)(nfeat + (size_t)gr * 128 + skc * 8);
        const int swz = (srow & 7);
#pragma unroll
        for (int j = 0; j < 8; ++j) {
            float4 x = np[2 * j], y = np[2 * j + 1];
            float tmp[8] = {x.x, x.y, x.z, x.w, y.x, y.y, y.z, y.w};
            bf16x8 f = pack8(tmp);
            const int kc = skc + j;
            *(bf16x8*)(Nb + srow * 256 + (((kc) ^ swz) * 16)) = f;
        }
    }
    __syncthreads();

    f32x4 acc[4][8];
#pragma unroll
    for (int mt = 0; mt < 4; ++mt)
#pragma unroll
        for (int nt = 0; nt < 8; ++nt) {
            acc[mt][nt][0] = bias4[mt].x; acc[mt][nt][1] = bias4[mt].y;
            acc[mt][nt][2] = bias4[mt].z; acc[mt][nt][3] = bias4[mt].w;
        }
#pragma unroll
    for (int nt = 0; nt < 8; ++nt) {
        const int r = nt * 16 + lrow;
        const int swz = (r & 7);
        bf16x8 Be[4];
#pragma unroll
        for (int kk = 0; kk < 4; ++kk)
            Be[kk] = *(const bf16x8*)(Nb + r * 256 + (((kk * 4 + lq) ^ swz) * 16));
#pragma unroll
        for (int mt = 0; mt < 4; ++mt)
#pragma unroll
            for (int kk = 0; kk < 4; ++kk)
                acc[mt][nt] = __builtin_amdgcn_mfma_f32_16x16x32_bf16(Wf[mt][kk], Be[kk], acc[mt][nt], 0, 0, 0);
    }

#pragma unroll
    for (int nt = 0; nt < 8; ++nt) {
        const int n = r0 + nt * 16 + lrow;
        if (n < N_NODES) {
#pragma unroll
            for (int mt = 0; mt < 4; ++mt) {
                const int c0 = colw + mt * 16 + lq * 4;
                ushort4 o;
                o.x = f2bf(acc[mt][nt][0]); o.y = f2bf(acc[mt][nt][1]);
                o.z = f2bf(acc[mt][nt][2]); o.w = f2bf(acc[mt][nt][3]);
                *(ushort4*)(Y + (size_t)n * 128 + c0) = o;
            }
        }
    }
}

// ---------------------------------------------------------------------------
// CSR build: count/rank -> scan  (slotOf folded into the edge kernel)
// ---------------------------------------------------------------------------
__global__ void count_rank_kernel(const int* __restrict__ dst,
                                  int* __restrict__ counts, int* __restrict__ rank) {
    const int e = blockIdx.x * blockDim.x + threadIdx.x;
    if (e < N_EDGES) rank[e] = atomicAdd(&counts[dst[e]], 1);
}

#define SCAN_T 1024
#define SCAN_CHUNK 49
__global__ void scan_kernel(const int* __restrict__ counts, int* __restrict__ off) {
    __shared__ int part[SCAN_T];
    const int t = threadIdx.x;
    const int base = t * SCAN_CHUNK;
    int s = 0;
    for (int k = 0; k < SCAN_CHUNK; ++k) {
        const int i = base + k;
        if (i < N_NODES) s += counts[i];
    }
    part[t] = s;
    __syncthreads();
    for (int d = 1; d < SCAN_T; d <<= 1) {
        int v = (t >= d) ? part[t - d] : 0;
        __syncthreads();
        part[t] += v;
        __syncthreads();
    }
    int excl = part[t] - s;
    for (int k = 0; k < SCAN_CHUNK; ++k) {
        const int i = base + k;
        if (i < N_NODES) { off[i] = excl; excl += counts[i]; }
    }
    if (t == SCAN_T - 1) off[N_NODES] = excl;
}

// ---------------------------------------------------------------------------
// Edge GEMM, swapped operands, single-buffer 2-barrier loop (R7 structure):
//   m[e] = relu(efeat[e] @ W2f + H1[src[e]] + b_ne)  -> mbuf[slot] (bf16)
// slot = offs[dst[e]] + rank[e] computed inline. Lane owns 4 consecutive
// out-cols per (mt,nt) -> ushort4 H1 loads and ushort4 mbuf stores.
// ---------------------------------------------------------------------------
__global__ __launch_bounds__(256, 3) void edge_gemm_scatter_kernel(
    const float* __restrict__ efeat, const int* __restrict__ src,
    const int* __restrict__ dst, const int* __restrict__ rank,
    const int* __restrict__ offs, const float* __restrict__ W2fT,
    const float* __restrict__ b_ne, const u16* __restrict__ H1,
    u16* __restrict__ mbuf) {

    __shared__ __align__(16) char Ab[128 * 64 * 2];   // 16 KB
    __shared__ int sS[128];
    __shared__ int sT[128];

    const int tid  = threadIdx.x;
    const int w    = tid >> 6;
    const int l    = tid & 63;
    const int lrow = l & 15;
    const int lq   = l >> 4;

    // A-side W2f fragments + per-reg bias (cols w*32+mt*16+lq*4+j)
    bf16x8 Wf[2][2];
    float4 bias4[2];
#pragma unroll
    for (int mt = 0; mt < 2; ++mt) {
        const int c = w * 32 + mt * 16 + lrow;
#pragma unroll
        for (int kk = 0; kk < 2; ++kk) {
            const float* wp = W2fT + c * 64 + kk * 32 + lq * 8;
            float tmp[8];
#pragma unroll
            for (int j = 0; j < 8; ++j) tmp[j] = wp[j];
            Wf[mt][kk] = pack8(tmp);
        }
        bias4[mt] = *(const float4*)(b_ne + w * 32 + mt * 16 + lq * 4);
    }

    const int srow = tid >> 1;
    const int skh  = (tid & 1) * 32;   // k-half in floats

    for (int tile = blockIdx.x; tile < NTILES; tile += gridDim.x) {
        const int e0 = tile * 128;

        if (tid < 128) {
            const int e = e0 + tid;
            sS[tid] = src[e];
            sT[tid] = offs[dst[e]] + rank[e];
        }
        // ---- stage efeat rows (sequential) -> bf16 swizzled LDS
        {
            const float4* ep = (const float4*)(efeat + (size_t)(e0 + srow) * 64 + skh);
            const int swz = (srow & 7) << 4;
#pragma unroll
            for (int j = 0; j < 4; ++j) {
                float4 x = ep[2 * j], y = ep[2 * j + 1];
                float tmp[8] = {x.x, x.y, x.z, x.w, y.x, y.y, y.z, y.w};
                bf16x8 f = pack8(tmp);
                *(bf16x8*)(Ab + ((srow * 128 + skh * 2 + j * 16) ^ swz)) = f;
            }
        }
        __syncthreads();   // Ab, sS, sT ready

        // ---- MFMA: D[out-col][edge] = W2f^T . efeat^T
        f32x4 acc[2][8];
#pragma unroll
        for (int mt = 0; mt < 2; ++mt)
#pragma unroll
            for (int nt = 0; nt < 8; ++nt) {
                acc[mt][nt][0] = bias4[mt].x; acc[mt][nt][1] = bias4[mt].y;
                acc[mt][nt][2] = bias4[mt].z; acc[mt][nt][3] = bias4[mt].w;
            }
#pragma unroll
        for (int nt = 0; nt < 8; ++nt) {
            const int r = nt * 16 + lrow;
            const int swz = (r & 7) << 4;
            bf16x8 Be0 = *(const bf16x8*)(Ab + ((r * 128 + lq * 16) ^ swz));
            bf16x8 Be1 = *(const bf16x8*)(Ab + ((r * 128 + 64 + lq * 16) ^ swz));
#pragma unroll
            for (int mt = 0; mt < 2; ++mt) {
                acc[mt][nt] = __builtin_amdgcn_mfma_f32_16x16x32_bf16(Wf[mt][0], Be0, acc[mt][nt], 0, 0, 0);
                acc[mt][nt] = __builtin_amdgcn_mfma_f32_16x16x32_bf16(Wf[mt][1], Be1, acc[mt][nt], 0, 0, 0);
            }
        }

        // ---- epilogue: lane owns cols w*32+mt*16+lq*4..+4 of edge nt*16+lrow
#pragma unroll
        for (int nt = 0; nt < 8; ++nt) {
            const int e  = nt * 16 + lrow;
            const int sn = sS[e];
            const int st = sT[e];
#pragma unroll
            for (int mt = 0; mt < 2; ++mt) {
                const int c0 = w * 32 + mt * 16 + lq * 4;
                ushort4 h4 = *(const ushort4*)(H1 + (size_t)sn * 128 + c0);
                ushort4 o;
                o.x = f2bf(fmaxf(acc[mt][nt][0] + bf2f(h4.x), 0.0f));
                o.y = f2bf(fmaxf(acc[mt][nt][1] + bf2f(h4.y), 0.0f));
                o.z = f2bf(fmaxf(acc[mt][nt][2] + bf2f(h4.z), 0.0f));
                o.w = f2bf(fmaxf(acc[mt][nt][3] + bf2f(h4.w), 0.0f));
                *(ushort4*)(mbuf + (size_t)st * 128 + c0) = o;
            }
        }
        __syncthreads();   // Ab/sS/sT free for next tile
    }
}

// ---------------------------------------------------------------------------
// Wave-per-node segment reduce + finalize (vectorized bf16x8 loads)
// ---------------------------------------------------------------------------
__global__ __launch_bounds__(256, 4) void reduce_kernel(
    const int* __restrict__ off, const u16* __restrict__ mbuf,
    const u16* __restrict__ HS, float* __restrict__ out) {
    const int n = (blockIdx.x * blockDim.x + threadIdx.x) >> 6;  // wave id = node
    if (n >= N_NODES) return;
    const int l  = threadIdx.x & 63;
    const int cs = l & 15;        // column slot (8 cols)
    const int rg = l >> 4;        // row group (4 rows in flight)
    const int s0 = off[n], s1 = off[n + 1];

    float facc[8];
#pragma unroll
    for (int i = 0; i < 8; ++i) facc[i] = 0.0f;
    for (int s = s0 + rg; s < s1; s += 4) {
        bf16x8 v = *(const bf16x8*)(mbuf + (size_t)s * 128 + cs * 8);
#pragma unroll
        for (int i = 0; i < 8; ++i) facc[i] += bf2f((u16)v[i]);
    }
#pragma unroll
    for (int i = 0; i < 8; ++i) {
        facc[i] += __shfl_xor(facc[i], 16, 64);
        facc[i] += __shfl_xor(facc[i], 32, 64);
    }
    if (rg == 0) {
        const int c = s1 - s0;
        const float inv = (c > 0) ? 1.0f / (float)c : 0.0f;
        bf16x8 hs = *(const bf16x8*)(HS + (size_t)n * 128 + cs * 8);
        float4 o0, o1;
        o0.x = facc[0] * inv + bf2f((u16)hs[0]);
        o0.y = facc[1] * inv + bf2f((u16)hs[1]);
        o0.z = facc[2] * inv + bf2f((u16)hs[2]);
        o0.w = facc[3] * inv + bf2f((u16)hs[3]);
        o1.x = facc[4] * inv + bf2f((u16)hs[4]);
        o1.y = facc[5] * inv + bf2f((u16)hs[5]);
        o1.z = facc[6] * inv + bf2f((u16)hs[6]);
        o1.w = facc[7] * inv + bf2f((u16)hs[7]);
        float* op = out + (size_t)n * 128 + cs * 8;
        *(float4*)op = o0;
        *(float4*)(op + 4) = o1;
    }
}

// ---------------------------------------------------------------------------
extern "C" void kernel_launch(void* const* d_in, const int* in_sizes, int n_in,
                              void* d_out, int out_size, void* d_ws, size_t ws_size,
                              hipStream_t stream) {
    const float* nfeat  = (const float*)d_in[0];
    const float* efeat  = (const float*)d_in[1];
    const int*   src    = (const int*)d_in[2];
    const int*   dst    = (const int*)d_in[3];
    const float* W_edge = (const float*)d_in[4];
    const float* W_ne   = (const float*)d_in[5];
    const float* b_ne   = (const float*)d_in[6];
    const float* W_self = (const float*)d_in[7];
    const float* b_self = (const float*)d_in[8];

    float* out = (float*)d_out;
    char* ws = (char*)d_ws;

    // ws layout (~234.1 MB; >=237 MB proven available in rounds 3-9)
    const size_t OFF_W2   = 0;          // 32768 B
    const size_t OFF_CNT  = 32768;      // 200000 B (+pad)
    const size_t OFF_OFFS = 232960;     // 200064 B (+pad)
    const size_t OFF_RANK = 433152;     // 3.2 MB
    const size_t OFF_H1   = 3633152;    // 12.8 MB
    const size_t OFF_HS   = 16433152;   // 12.8 MB
    const size_t OFF_M    = 29233152;   // 204.8 MB -> end 234033152

    float* W2fT = (float*)(ws + OFF_W2);
    int*   cnts = (int*)(ws + OFF_CNT);
    int*   offs = (int*)(ws + OFF_OFFS);
    int*   rank = (int*)(ws + OFF_RANK);
    u16*   H1   = (u16*)(ws + OFF_H1);
    u16*   HS   = (u16*)(ws + OFF_HS);
    u16*   mbuf = (u16*)(ws + OFF_M);

    prep_kernel<<<NODE_TILES + W2_BLOCKS + ZERO_BLOCKS, 256, 0, stream>>>(
        nfeat, W_ne, W_self, b_self, W_edge, H1, HS, W2fT, cnts);
    count_rank_kernel<<<(N_EDGES + 255) / 256, 256, 0, stream>>>(dst, cnts, rank);
    scan_kernel<<<1, SCAN_T, 0, stream>>>(cnts, offs);
    edge_gemm_scatter_kernel<<<2048, 256, 0, stream>>>(
        efeat, src, dst, rank, offs, W2fT, b_ne, H1, mbuf);
    reduce_kernel<<<(N_NODES * 64 + 255) / 256, 256, 0, stream>>>(offs, mbuf, HS, out);
}

// Round 11
// 354.582 us; speedup vs baseline: 1.7369x; 1.0028x over previous
//
#include <hip/hip_runtime.h>

#define N_NODES 50000
#define N_EDGES 800000
#define IN_DIM  128
#define EDGE_DIM 64
#define OUT_DIM 128
#define NTILES  (N_EDGES / 128)             // 6250 exact
#define NODE_TILES ((N_NODES + 127) / 128)  // 391
#define W2_BLOCKS 32
#define ZERO_BLOCKS 196                      // 196*256 = 50176 >= 50000

typedef __attribute__((ext_vector_type(8))) short bf16x8;
typedef __attribute__((ext_vector_type(4))) float f32x4;
typedef unsigned short u16;

__device__ __forceinline__ u16 f2bf(float f) {
    union { float f; unsigned u; } x; x.f = f;
    unsigned r = x.u + 0x7FFFu + ((x.u >> 16) & 1u);
    return (u16)(r >> 16);
}
__device__ __forceinline__ float bf2f(u16 h) {
    union { unsigned u; float f; } x; x.u = ((unsigned)h) << 16;
    return x.f;
}
__device__ __forceinline__ bf16x8 pack8(const float* v) {
    bf16x8 r;
#pragma unroll
    for (int i = 0; i < 8; ++i) r[i] = (short)f2bf(v[i]);
    return r;
}

// ---------------------------------------------------------------------------
// prep_kernel: three independent jobs by block range
//   blocks [0, NODE_TILES)              : MFMA node GEMM -> H1, HS (bf16)
//   blocks [NODE_TILES, +W2_BLOCKS)     : W2fT[o][c] fused weight
//   blocks [NODE_TILES+W2_BLOCKS, +196) : zero cnts
// ---------------------------------------------------------------------------
__global__ __launch_bounds__(256, 1) void prep_kernel(
    const float* __restrict__ nfeat, const float* __restrict__ W_ne,
    const float* __restrict__ W_self, const float* __restrict__ b_self,
    const float* __restrict__ W_edge,
    u16* __restrict__ H1, u16* __restrict__ HS,
    float* __restrict__ W2fT, int* __restrict__ cnts) {

    __shared__ __align__(16) char Nb[128 * 128 * 2];   // 32 KB bf16 tile

    const int bid = blockIdx.x;
    const int tid = threadIdx.x;

    if (bid >= NODE_TILES) {
        if (bid < NODE_TILES + W2_BLOCKS) {
            const int idx = (bid - NODE_TILES) * 256 + tid;
            const int c = idx >> 7;
            const int o = idx & 127;
            float acc = 0.0f;
            for (int i = 0; i < OUT_DIM; ++i)
                acc += W_edge[c * OUT_DIM + i] * W_ne[(IN_DIM + i) * OUT_DIM + o];
            W2fT[o * EDGE_DIM + c] = acc;
        } else {
            const int i = (bid - NODE_TILES - W2_BLOCKS) * 256 + tid;
            if (i < N_NODES) cnts[i] = 0;
        }
        return;
    }

    // ---- node GEMM tile (swapped operands, R9/R10-verified)
    const int w    = tid >> 6;
    const int l    = tid & 63;
    const int lrow = l & 15;
    const int lq   = l >> 4;

    const bool isSelf = (w >= 2);
    const float* W = isSelf ? W_self : W_ne;   // rows [0,128) of W_ne == W1
    const int colw = (w & 1) * 64;
    u16* Y = isSelf ? HS : H1;

    bf16x8 Wf[4][4];
#pragma unroll
    for (int mt = 0; mt < 4; ++mt) {
        const int c = colw + mt * 16 + lrow;
#pragma unroll
        for (int kk = 0; kk < 4; ++kk) {
            float tmp[8];
#pragma unroll
            for (int t = 0; t < 8; ++t) tmp[t] = W[(kk * 32 + lq * 8 + t) * 128 + c];
            Wf[mt][kk] = pack8(tmp);
        }
    }
    float4 bias4[4];
#pragma unroll
    for (int mt = 0; mt < 4; ++mt) {
        if (isSelf) bias4[mt] = *(const float4*)(b_self + colw + mt * 16 + lq * 4);
        else { bias4[mt].x = 0.f; bias4[mt].y = 0.f; bias4[mt].z = 0.f; bias4[mt].w = 0.f; }
    }

    const int srow = tid >> 1;
    const int skc  = (tid & 1) * 8;    // 16B-chunk index (8 floats per chunk)
    const int r0 = bid * 128;
    {
        const int gr = min(r0 + srow, N_NODES - 1);
        const float4* np = (const float4*)(nfeat + (size_t)gr * 128 + skc * 8);
        const int swz = (srow & 7);
#pragma unroll
        for (int j = 0; j < 8; ++j) {
            float4 x = np[2 * j], y = np[2 * j + 1];
            float tmp[8] = {x.x, x.y, x.z, x.w, y.x, y.y, y.z, y.w};
            bf16x8 f = pack8(tmp);
            const int kc = skc + j;
            *(bf16x8*)(Nb + srow * 256 + (((kc) ^ swz) * 16)) = f;
        }
    }
    __syncthreads();

    f32x4 acc[4][8];
#pragma unroll
    for (int mt = 0; mt < 4; ++mt)
#pragma unroll
        for (int nt = 0; nt < 8; ++nt) {
            acc[mt][nt][0] = bias4[mt].x; acc[mt][nt][1] = bias4[mt].y;
            acc[mt][nt][2] = bias4[mt].z; acc[mt][nt][3] = bias4[mt].w;
        }
#pragma unroll
    for (int nt = 0; nt < 8; ++nt) {
        const int r = nt * 16 + lrow;
        const int swz = (r & 7);
        bf16x8 Be[4];
#pragma unroll
        for (int kk = 0; kk < 4; ++kk)
            Be[kk] = *(const bf16x8*)(Nb + r * 256 + (((kk * 4 + lq) ^ swz) * 16));
#pragma unroll
        for (int mt = 0; mt < 4; ++mt)
#pragma unroll
            for (int kk = 0; kk < 4; ++kk)
                acc[mt][nt] = __builtin_amdgcn_mfma_f32_16x16x32_bf16(Wf[mt][kk], Be[kk], acc[mt][nt], 0, 0, 0);
    }

#pragma unroll
    for (int nt = 0; nt < 8; ++nt) {
        const int n = r0 + nt * 16 + lrow;
        if (n < N_NODES) {
#pragma unroll
            for (int mt = 0; mt < 4; ++mt) {
                const int c0 = colw + mt * 16 + lq * 4;
                ushort4 o;
                o.x = f2bf(acc[mt][nt][0]); o.y = f2bf(acc[mt][nt][1]);
                o.z = f2bf(acc[mt][nt][2]); o.w = f2bf(acc[mt][nt][3]);
                *(ushort4*)(Y + (size_t)n * 128 + c0) = o;
            }
        }
    }
}

// ---------------------------------------------------------------------------
// CSR build: count/rank -> scan  (slotOf computed inline in the edge kernel)
// ---------------------------------------------------------------------------
__global__ void count_rank_kernel(const int* __restrict__ dst,
                                  int* __restrict__ counts, int* __restrict__ rank) {
    const int e = blockIdx.x * blockDim.x + threadIdx.x;
    if (e < N_EDGES) rank[e] = atomicAdd(&counts[dst[e]], 1);
}

#define SCAN_T 1024
#define SCAN_CHUNK 49
__global__ void scan_kernel(const int* __restrict__ counts, int* __restrict__ off) {
    __shared__ int part[SCAN_T];
    const int t = threadIdx.x;
    const int base = t * SCAN_CHUNK;
    int s = 0;
    for (int k = 0; k < SCAN_CHUNK; ++k) {
        const int i = base + k;
        if (i < N_NODES) s += counts[i];
    }
    part[t] = s;
    __syncthreads();
    for (int d = 1; d < SCAN_T; d <<= 1) {
        int v = (t >= d) ? part[t - d] : 0;
        __syncthreads();
        part[t] += v;
        __syncthreads();
    }
    int excl = part[t] - s;
    for (int k = 0; k < SCAN_CHUNK; ++k) {
        const int i = base + k;
        if (i < N_NODES) { off[i] = excl; excl += counts[i]; }
    }
    if (t == SCAN_T - 1) off[N_NODES] = excl;
}

// ---------------------------------------------------------------------------
// Edge GEMM, swapped operands, single-buffer 2-barrier loop (R10-verified):
//   m[e] = relu(efeat[e] @ W2f + H1[src[e]] + b_ne)  -> mbuf[slot] (bf16)
// ---------------------------------------------------------------------------
__global__ __launch_bounds__(256, 3) void edge_gemm_scatter_kernel(
    const float* __restrict__ efeat, const int* __restrict__ src,
    const int* __restrict__ dst, const int* __restrict__ rank,
    const int* __restrict__ offs, const float* __restrict__ W2fT,
    const float* __restrict__ b_ne, const u16* __restrict__ H1,
    u16* __restrict__ mbuf) {

    __shared__ __align__(16) char Ab[128 * 64 * 2];   // 16 KB
    __shared__ int sS[128];
    __shared__ int sT[128];

    const int tid  = threadIdx.x;
    const int w    = tid >> 6;
    const int l    = tid & 63;
    const int lrow = l & 15;
    const int lq   = l >> 4;

    bf16x8 Wf[2][2];
    float4 bias4[2];
#pragma unroll
    for (int mt = 0; mt < 2; ++mt) {
        const int c = w * 32 + mt * 16 + lrow;
#pragma unroll
        for (int kk = 0; kk < 2; ++kk) {
            const float* wp = W2fT + c * 64 + kk * 32 + lq * 8;
            float tmp[8];
#pragma unroll
            for (int j = 0; j < 8; ++j) tmp[j] = wp[j];
            Wf[mt][kk] = pack8(tmp);
        }
        bias4[mt] = *(const float4*)(b_ne + w * 32 + mt * 16 + lq * 4);
    }

    const int srow = tid >> 1;
    const int skh  = (tid & 1) * 32;   // k-half in floats

    for (int tile = blockIdx.x; tile < NTILES; tile += gridDim.x) {
        const int e0 = tile * 128;

        if (tid < 128) {
            const int e = e0 + tid;
            sS[tid] = src[e];
            sT[tid] = offs[dst[e]] + rank[e];
        }
        {
            const float4* ep = (const float4*)(efeat + (size_t)(e0 + srow) * 64 + skh);
            const int swz = (srow & 7) << 4;
#pragma unroll
            for (int j = 0; j < 4; ++j) {
                float4 x = ep[2 * j], y = ep[2 * j + 1];
                float tmp[8] = {x.x, x.y, x.z, x.w, y.x, y.y, y.z, y.w};
                bf16x8 f = pack8(tmp);
                *(bf16x8*)(Ab + ((srow * 128 + skh * 2 + j * 16) ^ swz)) = f;
            }
        }
        __syncthreads();   // Ab, sS, sT ready

        f32x4 acc[2][8];
#pragma unroll
        for (int mt = 0; mt < 2; ++mt)
#pragma unroll
            for (int nt = 0; nt < 8; ++nt) {
                acc[mt][nt][0] = bias4[mt].x; acc[mt][nt][1] = bias4[mt].y;
                acc[mt][nt][2] = bias4[mt].z; acc[mt][nt][3] = bias4[mt].w;
            }
#pragma unroll
        for (int nt = 0; nt < 8; ++nt) {
            const int r = nt * 16 + lrow;
            const int swz = (r & 7) << 4;
            bf16x8 Be0 = *(const bf16x8*)(Ab + ((r * 128 + lq * 16) ^ swz));
            bf16x8 Be1 = *(const bf16x8*)(Ab + ((r * 128 + 64 + lq * 16) ^ swz));
#pragma unroll
            for (int mt = 0; mt < 2; ++mt) {
                acc[mt][nt] = __builtin_amdgcn_mfma_f32_16x16x32_bf16(Wf[mt][0], Be0, acc[mt][nt], 0, 0, 0);
                acc[mt][nt] = __builtin_amdgcn_mfma_f32_16x16x32_bf16(Wf[mt][1], Be1, acc[mt][nt], 0, 0, 0);
            }
        }

#pragma unroll
        for (int nt = 0; nt < 8; ++nt) {
            const int e  = nt * 16 + lrow;
            const int sn = sS[e];
            const int st = sT[e];
#pragma unroll
            for (int mt = 0; mt < 2; ++mt) {
                const int c0 = w * 32 + mt * 16 + lq * 4;
                ushort4 h4 = *(const ushort4*)(H1 + (size_t)sn * 128 + c0);
                ushort4 o;
                o.x = f2bf(fmaxf(acc[mt][nt][0] + bf2f(h4.x), 0.0f));
                o.y = f2bf(fmaxf(acc[mt][nt][1] + bf2f(h4.y), 0.0f));
                o.z = f2bf(fmaxf(acc[mt][nt][2] + bf2f(h4.z), 0.0f));
                o.w = f2bf(fmaxf(acc[mt][nt][3] + bf2f(h4.w), 0.0f));
                *(ushort4*)(mbuf + (size_t)st * 128 + c0) = o;
            }
        }
        __syncthreads();   // Ab/sS/sT free for next tile
    }
}

// ---------------------------------------------------------------------------
// Reduce v2: wave-per-node, 8 rows in flight.
//   lane l: rg = l>>3 (8 row groups), cs = l&7 (16 cols each, 2x bf16x8 = 32B)
//   3 shuffle-xor steps (8,16,32) combine row groups; rg==0 lanes store 64B.
// ---------------------------------------------------------------------------
__global__ __launch_bounds__(256, 4) void reduce_kernel(
    const int* __restrict__ off, const u16* __restrict__ mbuf,
    const u16* __restrict__ HS, float* __restrict__ out) {
    const int n = (blockIdx.x * blockDim.x + threadIdx.x) >> 6;  // wave id = node
    if (n >= N_NODES) return;
    const int l  = threadIdx.x & 63;
    const int cs = l & 7;         // column slot (16 cols)
    const int rg = l >> 3;        // row group (8 rows in flight)
    const int s0 = off[n], s1 = off[n + 1];

    float facc[16];
#pragma unroll
    for (int i = 0; i < 16; ++i) facc[i] = 0.0f;
    for (int s = s0 + rg; s < s1; s += 8) {
        const u16* rp = mbuf + (size_t)s * 128 + cs * 16;
        bf16x8 v0 = *(const bf16x8*)(rp);
        bf16x8 v1 = *(const bf16x8*)(rp + 8);
#pragma unroll
        for (int i = 0; i < 8; ++i) {
            facc[i]     += bf2f((u16)v0[i]);
            facc[i + 8] += bf2f((u16)v1[i]);
        }
    }
#pragma unroll
    for (int i = 0; i < 16; ++i) {
        facc[i] += __shfl_xor(facc[i], 8, 64);
        facc[i] += __shfl_xor(facc[i], 16, 64);
        facc[i] += __shfl_xor(facc[i], 32, 64);
    }
    if (rg == 0) {
        const int c = s1 - s0;
        const float inv = (c > 0) ? 1.0f / (float)c : 0.0f;
        const u16* hp = HS + (size_t)n * 128 + cs * 16;
        bf16x8 h0 = *(const bf16x8*)(hp);
        bf16x8 h1 = *(const bf16x8*)(hp + 8);
        float r[16];
#pragma unroll
        for (int i = 0; i < 8; ++i) {
            r[i]     = facc[i]     * inv + bf2f((u16)h0[i]);
            r[i + 8] = facc[i + 8] * inv + bf2f((u16)h1[i]);
        }
        float* op = out + (size_t)n * 128 + cs * 16;
#pragma unroll
        for (int q = 0; q < 4; ++q) {
            float4 o4;
            o4.x = r[q * 4 + 0]; o4.y = r[q * 4 + 1];
            o4.z = r[q * 4 + 2]; o4.w = r[q * 4 + 3];
            *(float4*)(op + q * 4) = o4;
        }
    }
}

// ---------------------------------------------------------------------------
extern "C" void kernel_launch(void* const* d_in, const int* in_sizes, int n_in,
                              void* d_out, int out_size, void* d_ws, size_t ws_size,
                              hipStream_t stream) {
    const float* nfeat  = (const float*)d_in[0];
    const float* efeat  = (const float*)d_in[1];
    const int*   src    = (const int*)d_in[2];
    const int*   dst    = (const int*)d_in[3];
    const float* W_edge = (const float*)d_in[4];
    const float* W_ne   = (const float*)d_in[5];
    const float* b_ne   = (const float*)d_in[6];
    const float* W_self = (const float*)d_in[7];
    const float* b_self = (const float*)d_in[8];

    float* out = (float*)d_out;
    char* ws = (char*)d_ws;

    // ws layout (~234.1 MB; >=237 MB proven available)
    const size_t OFF_W2   = 0;          // 32768 B
    const size_t OFF_CNT  = 32768;      // 200000 B (+pad)
    const size_t OFF_OFFS = 232960;     // 200064 B (+pad)
    const size_t OFF_RANK = 433152;     // 3.2 MB
    const size_t OFF_H1   = 3633152;    // 12.8 MB
    const size_t OFF_HS   = 16433152;   // 12.8 MB
    const size_t OFF_M    = 29233152;   // 204.8 MB -> end 234033152

    float* W2fT = (float*)(ws + OFF_W2);
    int*   cnts = (int*)(ws + OFF_CNT);
    int*   offs = (int*)(ws + OFF_OFFS);
    int*   rank = (int*)(ws + OFF_RANK);
    u16*   H1   = (u16*)(ws + OFF_H1);
    u16*   HS   = (u16*)(ws + OFF_HS);
    u16*   mbuf = (u16*)(ws + OFF_M);

    prep_kernel<<<NODE_TILES + W2_BLOCKS + ZERO_BLOCKS, 256, 0, stream>>>(
        nfeat, W_ne, W_self, b_self, W_edge, H1, HS, W2fT, cnts);
    count_rank_kernel<<<(N_EDGES + 255) / 256, 256, 0, stream>>>(dst, cnts, rank);
    scan_kernel<<<1, SCAN_T, 0, stream>>>(cnts, offs);
    edge_gemm_scatter_kernel<<<2048, 256, 0, stream>>>(
        efeat, src, dst, rank, offs, W2fT, b_ne, H1, mbuf);
    reduce_kernel<<<(N_NODES * 64 + 255) / 256, 256, 0, stream>>>(offs, mbuf, HS, out);
}

// Round 12
// 302.558 us; speedup vs baseline: 2.0355x; 1.1719x over previous
//
#include <hip/hip_runtime.h>

#define N_NODES 50000
#define N_EDGES 800000
#define IN_DIM  128
#define EDGE_DIM 64
#define OUT_DIM 128
#define NTILES  (N_EDGES / 128)             // 6250 exact
#define NODE_TILES ((N_NODES + 127) / 128)  // 391
#define W2_BLOCKS 32
#define CNT_BLOCKS ((N_EDGES + 255) / 256)  // 3125

typedef __attribute__((ext_vector_type(8))) short bf16x8;
typedef __attribute__((ext_vector_type(4))) float f32x4;
typedef unsigned short u16;

__device__ __forceinline__ u16 f2bf(float f) {
    union { float f; unsigned u; } x; x.f = f;
    unsigned r = x.u + 0x7FFFu + ((x.u >> 16) & 1u);
    return (u16)(r >> 16);
}
__device__ __forceinline__ float bf2f(u16 h) {
    union { unsigned u; float f; } x; x.u = ((unsigned)h) << 16;
    return x.f;
}
__device__ __forceinline__ bf16x8 pack8(const float* v) {
    bf16x8 r;
#pragma unroll
    for (int i = 0; i < 8; ++i) r[i] = (short)f2bf(v[i]);
    return r;
}
// swizzled byte offset into a [128 rows][128 u16] LDS tile; chunk = u16col/4
__device__ __forceinline__ int hswz(int r, int chunk) {
    return r * 256 + ((chunk ^ ((((r & 7) ^ ((r >> 3) & 7))) << 2)) * 8);
}

// ---------------------------------------------------------------------------
// prep_kernel: three independent jobs by block range
//   blocks [0, NODE_TILES)            : MFMA node GEMM -> H1, HS (bf16)
//   blocks [NODE_TILES, +W2_BLOCKS)   : W2fT fused weight
//   blocks [.., +CNT_BLOCKS)          : count/rank atomics (cnts pre-zeroed)
// ---------------------------------------------------------------------------
__global__ __launch_bounds__(256, 1) void prep_kernel(
    const float* __restrict__ nfeat, const float* __restrict__ W_ne,
    const float* __restrict__ W_self, const float* __restrict__ b_self,
    const float* __restrict__ W_edge, const int* __restrict__ dst,
    u16* __restrict__ H1, u16* __restrict__ HS,
    float* __restrict__ W2fT, int* __restrict__ cnts, int* __restrict__ rank) {

    __shared__ __align__(16) char Nb[128 * 128 * 2];   // 32 KB bf16 tile

    const int bid = blockIdx.x;
    const int tid = threadIdx.x;

    if (bid >= NODE_TILES) {
        if (bid < NODE_TILES + W2_BLOCKS) {
            const int idx = (bid - NODE_TILES) * 256 + tid;
            const int c = idx >> 7;
            const int o = idx & 127;
            float acc = 0.0f;
            for (int i = 0; i < OUT_DIM; ++i)
                acc += W_edge[c * OUT_DIM + i] * W_ne[(IN_DIM + i) * OUT_DIM + o];
            W2fT[o * EDGE_DIM + c] = acc;
        } else {
            const int e = (bid - NODE_TILES - W2_BLOCKS) * 256 + tid;
            if (e < N_EDGES) rank[e] = atomicAdd(&cnts[dst[e]], 1);
        }
        return;
    }

    // ---- node GEMM tile (swapped operands, R9/R10-verified)
    const int w    = tid >> 6;
    const int l    = tid & 63;
    const int lrow = l & 15;
    const int lq   = l >> 4;

    const bool isSelf = (w >= 2);
    const float* W = isSelf ? W_self : W_ne;   // rows [0,128) of W_ne == W1
    const int colw = (w & 1) * 64;
    u16* Y = isSelf ? HS : H1;

    bf16x8 Wf[4][4];
#pragma unroll
    for (int mt = 0; mt < 4; ++mt) {
        const int c = colw + mt * 16 + lrow;
#pragma unroll
        for (int kk = 0; kk < 4; ++kk) {
            float tmp[8];
#pragma unroll
            for (int t = 0; t < 8; ++t) tmp[t] = W[(kk * 32 + lq * 8 + t) * 128 + c];
            Wf[mt][kk] = pack8(tmp);
        }
    }
    float4 bias4[4];
#pragma unroll
    for (int mt = 0; mt < 4; ++mt) {
        if (isSelf) bias4[mt] = *(const float4*)(b_self + colw + mt * 16 + lq * 4);
        else { bias4[mt].x = 0.f; bias4[mt].y = 0.f; bias4[mt].z = 0.f; bias4[mt].w = 0.f; }
    }

    const int srow = tid >> 1;
    const int skc  = (tid & 1) * 8;    // 16B-chunk index (8 floats per chunk)
    const int r0 = bid * 128;
    {
        const int gr = min(r0 + srow, N_NODES - 1);
        const float4* np = (const float4*)(nfeat + (size_t)gr * 128 + skc * 8);
        const int swz = (srow & 7);
#pragma unroll
        for (int j = 0; j < 8; ++j) {
            float4 x = np[2 * j], y = np[2 * j + 1];
            float tmp[8] = {x.x, x.y, x.z, x.w, y.x, y.y, y.z, y.w};
            bf16x8 f = pack8(tmp);
            const int kc = skc + j;
            *(bf16x8*)(Nb + srow * 256 + (((kc) ^ swz) * 16)) = f;
        }
    }
    __syncthreads();

    f32x4 acc[4][8];
#pragma unroll
    for (int mt = 0; mt < 4; ++mt)
#pragma unroll
        for (int nt = 0; nt < 8; ++nt) {
            acc[mt][nt][0] = bias4[mt].x; acc[mt][nt][1] = bias4[mt].y;
            acc[mt][nt][2] = bias4[mt].z; acc[mt][nt][3] = bias4[mt].w;
        }
#pragma unroll
    for (int nt = 0; nt < 8; ++nt) {
        const int r = nt * 16 + lrow;
        const int swz = (r & 7);
        bf16x8 Be[4];
#pragma unroll
        for (int kk = 0; kk < 4; ++kk)
            Be[kk] = *(const bf16x8*)(Nb + r * 256 + (((kk * 4 + lq) ^ swz) * 16));
#pragma unroll
        for (int mt = 0; mt < 4; ++mt)
#pragma unroll
            for (int kk = 0; kk < 4; ++kk)
                acc[mt][nt] = __builtin_amdgcn_mfma_f32_16x16x32_bf16(Wf[mt][kk], Be[kk], acc[mt][nt], 0, 0, 0);
    }

#pragma unroll
    for (int nt = 0; nt < 8; ++nt) {
        const int n = r0 + nt * 16 + lrow;
        if (n < N_NODES) {
#pragma unroll
            for (int mt = 0; mt < 4; ++mt) {
                const int c0 = colw + mt * 16 + lq * 4;
                ushort4 o;
                o.x = f2bf(acc[mt][nt][0]); o.y = f2bf(acc[mt][nt][1]);
                o.z = f2bf(acc[mt][nt][2]); o.w = f2bf(acc[mt][nt][3]);
                *(ushort4*)(Y + (size_t)n * 128 + c0) = o;
            }
        }
    }
}

// ---------------------------------------------------------------------------
#define SCAN_T 1024
#define SCAN_CHUNK 49
__global__ void scan_kernel(const int* __restrict__ counts, int* __restrict__ off) {
    __shared__ int part[SCAN_T];
    const int t = threadIdx.x;
    const int base = t * SCAN_CHUNK;
    int s = 0;
    for (int k = 0; k < SCAN_CHUNK; ++k) {
        const int i = base + k;
        if (i < N_NODES) s += counts[i];
    }
    part[t] = s;
    __syncthreads();
    for (int d = 1; d < SCAN_T; d <<= 1) {
        int v = (t >= d) ? part[t - d] : 0;
        __syncthreads();
        part[t] += v;
        __syncthreads();
    }
    int excl = part[t] - s;
    for (int k = 0; k < SCAN_CHUNK; ++k) {
        const int i = base + k;
        if (i < N_NODES) { off[i] = excl; excl += counts[i]; }
    }
    if (t == SCAN_T - 1) off[N_NODES] = excl;
}

// ---------------------------------------------------------------------------
// Edge GEMM v3: all random global traffic in 128-B segments.
//   - H1 rows gathered by 16-lane groups (256B contiguous) into swizzled HMb
//   - epilogue updates HMb in place (same lane, same address)
//   - mbuf scatter written by 16-lane groups (256B contiguous per row)
// ---------------------------------------------------------------------------
__global__ __launch_bounds__(256, 3) void edge_gemm_scatter_kernel(
    const float* __restrict__ efeat, const int* __restrict__ src,
    const int* __restrict__ dst, const int* __restrict__ rank,
    const int* __restrict__ offs, const float* __restrict__ W2fT,
    const float* __restrict__ b_ne, const u16* __restrict__ H1,
    u16* __restrict__ mbuf) {

    __shared__ __align__(16) char Ab[128 * 64 * 2];    // 16 KB A-tile
    __shared__ __align__(16) char HMb[128 * 128 * 2];  // 32 KB H1/m tile (swizzled)
    __shared__ int sS[128];
    __shared__ int sT[128];

    const int tid  = threadIdx.x;
    const int w    = tid >> 6;
    const int l    = tid & 63;
    const int lrow = l & 15;
    const int lq   = l >> 4;
    const int g    = tid >> 4;     // 16-lane group id (0..15)
    const int gi   = tid & 15;     // lane within group

    bf16x8 Wf[2][2];
    float4 bias4[2];
#pragma unroll
    for (int mt = 0; mt < 2; ++mt) {
        const int c = w * 32 + mt * 16 + lrow;
#pragma unroll
        for (int kk = 0; kk < 2; ++kk) {
            const float* wp = W2fT + c * 64 + kk * 32 + lq * 8;
            float tmp[8];
#pragma unroll
            for (int j = 0; j < 8; ++j) tmp[j] = wp[j];
            Wf[mt][kk] = pack8(tmp);
        }
        bias4[mt] = *(const float4*)(b_ne + w * 32 + mt * 16 + lq * 4);
    }

    const int srow = tid >> 1;
    const int skh  = (tid & 1) * 32;   // k-half in floats

    for (int tile = blockIdx.x; tile < NTILES; tile += gridDim.x) {
        const int e0 = tile * 128;

        if (tid < 128) {
            const int e = e0 + tid;
            sS[tid] = src[e];
            sT[tid] = offs[dst[e]] + rank[e];
        }
        // ---- stage efeat rows (sequential) -> bf16 swizzled LDS
        {
            const float4* ep = (const float4*)(efeat + (size_t)(e0 + srow) * 64 + skh);
            const int swz = (srow & 7) << 4;
#pragma unroll
            for (int j = 0; j < 4; ++j) {
                float4 x = ep[2 * j], y = ep[2 * j + 1];
                float tmp[8] = {x.x, x.y, x.z, x.w, y.x, y.y, y.z, y.w};
                bf16x8 f = pack8(tmp);
                *(bf16x8*)(Ab + ((srow * 128 + skh * 2 + j * 16) ^ swz)) = f;
            }
        }
        __syncthreads();   // B1: Ab, sS, sT ready; prev-tile HMb consumers done

        // ---- issue H1 gather (256B-contiguous per row; latency hides under MFMA)
        bf16x8 hreg[8];
#pragma unroll
        for (int k = 0; k < 8; ++k) {
            const int r = g * 8 + k;
            hreg[k] = *(const bf16x8*)(H1 + (size_t)sS[r] * 128 + gi * 8);
        }

        // ---- MFMA: D[out-col][edge] = W2f^T . efeat^T
        f32x4 acc[2][8];
#pragma unroll
        for (int mt = 0; mt < 2; ++mt)
#pragma unroll
            for (int nt = 0; nt < 8; ++nt) {
                acc[mt][nt][0] = bias4[mt].x; acc[mt][nt][1] = bias4[mt].y;
                acc[mt][nt][2] = bias4[mt].z; acc[mt][nt][3] = bias4[mt].w;
            }
#pragma unroll
        for (int nt = 0; nt < 8; ++nt) {
            const int r = nt * 16 + lrow;
            const int swz = (r & 7) << 4;
            bf16x8 Be0 = *(const bf16x8*)(Ab + ((r * 128 + lq * 16) ^ swz));
            bf16x8 Be1 = *(const bf16x8*)(Ab + ((r * 128 + 64 + lq * 16) ^ swz));
#pragma unroll
            for (int mt = 0; mt < 2; ++mt) {
                acc[mt][nt] = __builtin_amdgcn_mfma_f32_16x16x32_bf16(Wf[mt][0], Be0, acc[mt][nt], 0, 0, 0);
                acc[mt][nt] = __builtin_amdgcn_mfma_f32_16x16x32_bf16(Wf[mt][1], Be1, acc[mt][nt], 0, 0, 0);
            }
        }

        // ---- park gathered H1 rows into swizzled HMb
#pragma unroll
        for (int k = 0; k < 8; ++k) {
            const int r = g * 8 + k;
            *(bf16x8*)(HMb + hswz(r, 2 * gi)) = hreg[k];
        }
        __syncthreads();   // B2: HMb holds H1 rows

        // ---- epilogue: v = relu(acc + H1) written back in place
#pragma unroll
        for (int nt = 0; nt < 8; ++nt) {
            const int e = nt * 16 + lrow;
#pragma unroll
            for (int mt = 0; mt < 2; ++mt) {
                const int c0 = w * 32 + mt * 16 + lq * 4;
                const int byte = hswz(e, c0 >> 2);
                ushort4 h4 = *(const ushort4*)(HMb + byte);
                ushort4 o;
                o.x = f2bf(fmaxf(acc[mt][nt][0] + bf2f(h4.x), 0.0f));
                o.y = f2bf(fmaxf(acc[mt][nt][1] + bf2f(h4.y), 0.0f));
                o.z = f2bf(fmaxf(acc[mt][nt][2] + bf2f(h4.z), 0.0f));
                o.w = f2bf(fmaxf(acc[mt][nt][3] + bf2f(h4.w), 0.0f));
                *(ushort4*)(HMb + byte) = o;
            }
        }
        __syncthreads();   // B3: HMb holds m rows

        // ---- coalesced scatter: 16-lane groups write 256B-contiguous rows
#pragma unroll
        for (int k = 0; k < 8; ++k) {
            const int r  = g * 8 + k;
            const int st = sT[r];
            bf16x8 v = *(const bf16x8*)(HMb + hswz(r, 2 * gi));
            *(bf16x8*)(mbuf + (size_t)st * 128 + gi * 8) = v;
        }
        // B1 of next iteration protects HMb reuse
    }
}

// ---------------------------------------------------------------------------
// Reduce: wave-per-node, 8 rows in flight (R11 structure)
// ---------------------------------------------------------------------------
__global__ __launch_bounds__(256, 4) void reduce_kernel(
    const int* __restrict__ off, const u16* __restrict__ mbuf,
    const u16* __restrict__ HS, float* __restrict__ out) {
    const int n = (blockIdx.x * blockDim.x + threadIdx.x) >> 6;  // wave id = node
    if (n >= N_NODES) return;
    const int l  = threadIdx.x & 63;
    const int cs = l & 7;         // column slot (16 cols)
    const int rg = l >> 3;        // row group (8 rows in flight)
    const int s0 = off[n], s1 = off[n + 1];

    float facc[16];
#pragma unroll
    for (int i = 0; i < 16; ++i) facc[i] = 0.0f;
    for (int s = s0 + rg; s < s1; s += 8) {
        const u16* rp = mbuf + (size_t)s * 128 + cs * 16;
        bf16x8 v0 = *(const bf16x8*)(rp);
        bf16x8 v1 = *(const bf16x8*)(rp + 8);
#pragma unroll
        for (int i = 0; i < 8; ++i) {
            facc[i]     += bf2f((u16)v0[i]);
            facc[i + 8] += bf2f((u16)v1[i]);
        }
    }
#pragma unroll
    for (int i = 0; i < 16; ++i) {
        facc[i] += __shfl_xor(facc[i], 8, 64);
        facc[i] += __shfl_xor(facc[i], 16, 64);
        facc[i] += __shfl_xor(facc[i], 32, 64);
    }
    if (rg == 0) {
        const int c = s1 - s0;
        const float inv = (c > 0) ? 1.0f / (float)c : 0.0f;
        const u16* hp = HS + (size_t)n * 128 + cs * 16;
        bf16x8 h0 = *(const bf16x8*)(hp);
        bf16x8 h1 = *(const bf16x8*)(hp + 8);
        float r[16];
#pragma unroll
        for (int i = 0; i < 8; ++i) {
            r[i]     = facc[i]     * inv + bf2f((u16)h0[i]);
            r[i + 8] = facc[i + 8] * inv + bf2f((u16)h1[i]);
        }
        float* op = out + (size_t)n * 128 + cs * 16;
#pragma unroll
        for (int q = 0; q < 4; ++q) {
            float4 o4;
            o4.x = r[q * 4 + 0]; o4.y = r[q * 4 + 1];
            o4.z = r[q * 4 + 2]; o4.w = r[q * 4 + 3];
            *(float4*)(op + q * 4) = o4;
        }
    }
}

// ---------------------------------------------------------------------------
extern "C" void kernel_launch(void* const* d_in, const int* in_sizes, int n_in,
                              void* d_out, int out_size, void* d_ws, size_t ws_size,
                              hipStream_t stream) {
    const float* nfeat  = (const float*)d_in[0];
    const float* efeat  = (const float*)d_in[1];
    const int*   src    = (const int*)d_in[2];
    const int*   dst    = (const int*)d_in[3];
    const float* W_edge = (const float*)d_in[4];
    const float* W_ne   = (const float*)d_in[5];
    const float* b_ne   = (const float*)d_in[6];
    const float* W_self = (const float*)d_in[7];
    const float* b_self = (const float*)d_in[8];

    float* out = (float*)d_out;
    char* ws = (char*)d_ws;

    // ws layout (~234.1 MB; >=237 MB proven available)
    const size_t OFF_W2   = 0;          // 32768 B
    const size_t OFF_CNT  = 32768;      // 200000 B (+pad)
    const size_t OFF_OFFS = 232960;     // 200064 B (+pad)
    const size_t OFF_RANK = 433152;     // 3.2 MB
    const size_t OFF_H1   = 3633152;    // 12.8 MB
    const size_t OFF_HS   = 16433152;   // 12.8 MB
    const size_t OFF_M    = 29233152;   // 204.8 MB -> end 234033152

    float* W2fT = (float*)(ws + OFF_W2);
    int*   cnts = (int*)(ws + OFF_CNT);
    int*   offs = (int*)(ws + OFF_OFFS);
    int*   rank = (int*)(ws + OFF_RANK);
    u16*   H1   = (u16*)(ws + OFF_H1);
    u16*   HS   = (u16*)(ws + OFF_HS);
    u16*   mbuf = (u16*)(ws + OFF_M);

    hipMemsetAsync(cnts, 0, N_NODES * sizeof(int), stream);
    prep_kernel<<<NODE_TILES + W2_BLOCKS + CNT_BLOCKS, 256, 0, stream>>>(
        nfeat, W_ne, W_self, b_self, W_edge, dst, H1, HS, W2fT, cnts, rank);
    scan_kernel<<<1, SCAN_T, 0, stream>>>(cnts, offs);
    edge_gemm_scatter_kernel<<<2048, 256, 0, stream>>>(
        efeat, src, dst, rank, offs, W2fT, b_ne, H1, mbuf);
    reduce_kernel<<<(N_NODES * 64 + 255) / 256, 256, 0, stream>>>(offs, mbuf, HS, out);
}